// Round 10
// baseline (538.596 us; speedup 1.0000x reference)
//
#include <hip/hip_runtime.h>
#include <hip/hip_bf16.h>
#include <stddef.h>
#include <stdint.h>

#define NB   4096
#define NC   10
#define DIN  3072
#define DD   256
#define KCB  512
#define KSPLIT 6
#define KC   (DIN / KSPLIT)   /* 512 */
#define TM   128
#define TGRID 42              /* max tiles: sum ceil(cnt/128) <= 32+10 = 42 */
#define NIT  (KC / 32)        /* 16 */
#define NENC (TGRID * KSPLIT) /* 252 enc blocks */
#define NDEC 96               /* 12 col-tiles x 8 row-tiles */

/* packed encW strides (u16 elems): [c][nh 2][ks 6][it 16][cg 8][fg 4][fr 16][8] */
#define PW_C  786432
#define PW_NH 393216
#define PW_KS 65536
#define PW_IT 4096

typedef unsigned short u16;
typedef short s16x8 __attribute__((ext_vector_type(8)));
typedef short s16x4 __attribute__((ext_vector_type(4)));
typedef float f32x4 __attribute__((ext_vector_type(4)));

// f32 -> (hi bf16, lo bf16), both round-to-nearest-even
__device__ inline void f2bf2(float f, u16& h, u16& l) {
    unsigned uf = __builtin_bit_cast(unsigned, f);
    unsigned uh = (uf + 0x7FFFu + ((uf >> 16) & 1u)) >> 16;
    h = (u16)uh;
    float fh = __builtin_bit_cast(float, uh << 16);
    float r = f - fh;
    unsigned ur = __builtin_bit_cast(unsigned, r);
    l = (u16)((ur + 0x7FFFu + ((ur >> 16) & 1u)) >> 16);
}

// async global->LDS DMA, 16B per lane (dest = uniform base + lane*16)
__device__ __forceinline__ void gl16(const u16* g, u16* l) {
    __builtin_amdgcn_global_load_lds(
        (const __attribute__((address_space(1))) unsigned int*)(uintptr_t)g,
        (__attribute__((address_space(3))) unsigned int*)(unsigned int)(uintptr_t)l,
        16, 0, 0);
}

// ---------------- fused prologue ----------------
// blk 0: binning + tilemap (+ zero gather counter meta[61]); blk 1,2: codebook
// norms; blk 3..1922: encW pack; blk 1923..2114: dW transpose+split;
// blk 2115..2146: cb f32 transpose
__global__ __launch_bounds__(256) void k_wtp(
    const int* __restrict__ label, const float* __restrict__ cb,
    const float* __restrict__ encW, const float* __restrict__ dW,
    int* __restrict__ meta, int* __restrict__ order, float* __restrict__ cbn,
    u16* __restrict__ WtH, u16* __restrict__ WtL,
    u16* __restrict__ dWtH, u16* __restrict__ dWtL, float* __restrict__ cbt)
{
    const int t = threadIdx.x;
    const int bid = blockIdx.x;
    if (bid == 0) {
        __shared__ int cnt_s[NC], cur_s[NC], off_s[NC];
        if (t < NC) { cnt_s[t] = 0; cur_s[t] = 0; }
        __syncthreads();
        for (int b = t; b < NB; b += 256) atomicAdd(&cnt_s[label[b]], 1);
        __syncthreads();
        if (t == 0) {
            int o = 0;
            for (int c = 0; c < NC; ++c) {
                off_s[c] = o; meta[c] = cnt_s[c]; meta[32 + c] = o; o += cnt_s[c];
            }
            meta[32 + NC] = o;
            meta[61] = 0;                       // gather last-block counter
            int ntl = 0;
            for (int c = 0; c < NC; ++c)
                for (int r0 = 0; r0 < cnt_s[c]; r0 += TM) {
                    meta[64 + 2 * ntl] = c; meta[65 + 2 * ntl] = r0; ++ntl;
                }
            meta[63] = ntl;
        }
        __syncthreads();
        for (int b = t; b < NB; b += 256) {
            int c = label[b];
            int p = atomicAdd(&cur_s[c], 1);
            order[off_s[c] + p] = b;
        }
        return;
    }
    if (bid <= 2) {
        int k = (bid - 1) * 256 + t;
        if (k < KCB) {
            const float* r = cb + (size_t)k * DD;
            float a = 0.f;
#pragma unroll 4
            for (int i = 0; i < 64; ++i) {
                float4 v = *(const float4*)(r + i * 4);
                a = fmaf(v.x, v.x, fmaf(v.y, v.y, fmaf(v.z, v.z, fmaf(v.w, v.w, a))));
            }
            cbn[k] = a;
        }
        return;
    }
    // ---- transpose machinery (64x64 tiles) ----
    const int wb = bid - 3;
    const float* src; int lsrc, ldst, k0, n0;
    u16 *dH = nullptr, *dL = nullptr; float* fdst = nullptr;
    int encw_c = -1;
    if (wb < 1920) {
        int c = wb / 192, rem = wb % 192;
        int kt = rem >> 2, nt = rem & 3;
        k0 = kt * 64; n0 = nt * 64;
        src = encW + (size_t)c * DIN * DD;  lsrc = DD;
        encw_c = c; ldst = 0;
    } else if (wb < 2112) {
        int rem = wb - 1920;
        int kt = rem / 48, nt = rem % 48;
        k0 = kt * 64; n0 = nt * 64;
        src = dW; lsrc = DIN;
        dH = dWtH; dL = dWtL; ldst = DD;
    } else {
        int rem = wb - 2112;          // cb: src rows = codes (512), cols = k (256)
        int kt = rem >> 2, nt = rem & 3;
        k0 = kt * 64; n0 = nt * 64;
        src = cb; lsrc = DD;
        fdst = cbt; ldst = KCB;
    }
    __shared__ float tile[64][65];
    const int trow = t >> 4, tc4 = t & 15;
#pragma unroll
    for (int j = 0; j < 4; ++j) {
        int kk = trow * 4 + j;
        float4 v = *(const float4*)&src[(size_t)(k0 + kk) * lsrc + n0 + tc4 * 4];
        tile[kk][tc4 * 4 + 0] = v.x; tile[kk][tc4 * 4 + 1] = v.y;
        tile[kk][tc4 * 4 + 2] = v.z; tile[kk][tc4 * 4 + 3] = v.w;
    }
    __syncthreads();
    const int n = n0 + (t >> 2), q = t & 3;
    if (fdst) {
#pragma unroll
        for (int j = 0; j < 4; ++j) {
            float4 o = {tile[q * 16 + 4 * j + 0][n - n0], tile[q * 16 + 4 * j + 1][n - n0],
                        tile[q * 16 + 4 * j + 2][n - n0], tile[q * 16 + 4 * j + 3][n - n0]};
            *(float4*)&fdst[(size_t)n * ldst + k0 + q * 16 + 4 * j] = o;
        }
        return;
    }
    s16x8 vh0, vh1, vl0, vl1;
#pragma unroll
    for (int i = 0; i < 8; ++i) {
        u16 h, l;
        f2bf2(tile[q * 16 + i][n - n0], h, l);
        vh0[i] = (short)h; vl0[i] = (short)l;
    }
#pragma unroll
    for (int i = 0; i < 8; ++i) {
        u16 h, l;
        f2bf2(tile[q * 16 + 8 + i][n - n0], h, l);
        vh1[i] = (short)h; vl1[i] = (short)l;
    }
    if (encw_c >= 0) {
        // packed store: [c][nh][ks][it][cg][fg][fr][8]
        const int nh = n >> 7, cg = (n & 127) >> 4, fr2 = n & 15;
        const size_t nbase = (size_t)encw_c * PW_C + (size_t)nh * PW_NH
                           + (size_t)cg * 512 + (size_t)fr2 * 8;
        int ko = (k0 >> 3) + 2 * q;
        {
            int ks2 = ko >> 6, r2 = ko & 63, it2 = r2 >> 2, fg2 = r2 & 3;
            size_t o = nbase + (size_t)ks2 * PW_KS + (size_t)it2 * PW_IT + (size_t)fg2 * 128;
            *(s16x8*)&WtH[o] = vh0; *(s16x8*)&WtL[o] = vl0;
        }
        {
            int ko1 = ko + 1;
            int ks2 = ko1 >> 6, r2 = ko1 & 63, it2 = r2 >> 2, fg2 = r2 & 3;
            size_t o = nbase + (size_t)ks2 * PW_KS + (size_t)it2 * PW_IT + (size_t)fg2 * 128;
            *(s16x8*)&WtH[o] = vh1; *(s16x8*)&WtL[o] = vl1;
        }
        return;
    }
    u16* oH = dH + (size_t)n * ldst + k0 + q * 16;
    u16* oL = dL + (size_t)n * ldst + k0 + q * 16;
    *(s16x8*)oH = vh0; *(s16x8*)(oH + 8) = vh1;
    *(s16x8*)oL = vl0; *(s16x8*)(oL + 8) = vl1;
}

// ---------------- fused encoder GEMM (v4, verified) + decoder GEMM ----------------
#define ENC_STEP(IT, PB, L0, L1, C0, C1)                                        \
    {                                                                           \
        if ((IT) + 1 < NIT) { asm volatile("s_waitcnt vmcnt(6)" ::: "memory"); } \
        else                { asm volatile("s_waitcnt vmcnt(0)" ::: "memory"); } \
        asm volatile("s_waitcnt lgkmcnt(0)" ::: "memory");                      \
        __builtin_amdgcn_s_barrier();                                           \
        __builtin_amdgcn_sched_barrier(0);                                      \
        s16x8 aH[4], aL[4], bH[4], bL[4];                                       \
        _Pragma("unroll")                                                       \
        for (int mt = 0; mt < 4; ++mt) {                                        \
            aH[mt] = *(const s16x8*)&AsH[(wr * 4 + mt) * 512 + arb];            \
            aL[mt] = *(const s16x8*)&AsL[(wr * 4 + mt) * 512 + arb];            \
        }                                                                       \
        _Pragma("unroll")                                                       \
        for (int ct = 0; ct < 4; ++ct) {                                        \
            bH[ct] = *(const s16x8*)&BsH[PB][ct * 512 + brb];                   \
            bL[ct] = *(const s16x8*)&BsL[PB][ct * 512 + brb];                   \
        }                                                                       \
        asm volatile("s_waitcnt lgkmcnt(0)" ::: "memory");                      \
        __builtin_amdgcn_sched_barrier(0);                                      \
        __builtin_amdgcn_s_barrier();                                           \
        __builtin_amdgcn_sched_barrier(0);                                      \
        if ((IT) + 2 < NIT) {                                                   \
            L0 = *(const float4*)(xp + ((IT) + 2) * 32);                        \
            L1 = *(const float4*)(xp + ((IT) + 2) * 32 + 4);                    \
            __builtin_amdgcn_sched_barrier(0);                                  \
            const u16* g_ = gchunk + (size_t)((IT) + 2) * PW_IT;                \
            u16* l_ = lchunk + (PB) * 8192;                                     \
            _Pragma("unroll")                                                   \
            for (int i = 0; i < 4; ++i) gl16(g_ + i * 512, l_ + i * 512);       \
            __builtin_amdgcn_sched_barrier(0);                                  \
        }                                                                       \
        __builtin_amdgcn_s_setprio(1);                                          \
        _Pragma("unroll")                                                       \
        for (int ct = 0; ct < 4; ++ct) {                                        \
            _Pragma("unroll")                                                   \
            for (int mt = 0; mt < 4; ++mt) {                                    \
                acc[mt][ct] = __builtin_amdgcn_mfma_f32_16x16x32_bf16(aH[mt], bH[ct], acc[mt][ct], 0, 0, 0); \
                acc[mt][ct] = __builtin_amdgcn_mfma_f32_16x16x32_bf16(aL[mt], bH[ct], acc[mt][ct], 0, 0, 0); \
                acc[mt][ct] = __builtin_amdgcn_mfma_f32_16x16x32_bf16(aH[mt], bL[ct], acc[mt][ct], 0, 0, 0); \
            }                                                                   \
        }                                                                       \
        __builtin_amdgcn_s_setprio(0);                                          \
        if ((IT) + 1 < NIT) {                                                   \
            if ((IT) + 2 < NIT) { asm volatile("s_waitcnt vmcnt(10)" ::: "memory"); } \
            else                { asm volatile("s_waitcnt vmcnt(4)"  ::: "memory"); } \
            cvt_store(C0, C1);                                                  \
        }                                                                       \
    }

__global__ __launch_bounds__(512, 2) void k_encdec(
    const float* __restrict__ x, const u16* __restrict__ WpH, const u16* __restrict__ WpL,
    const int* __restrict__ order, const int* __restrict__ meta, float* __restrict__ zpart,
    const float* __restrict__ cb, const u16* __restrict__ dWtH, const u16* __restrict__ dWtL,
    const float* __restrict__ db, float* __restrict__ dcb)
{
    __shared__ __align__(16) u16 smem[40960];   // 81920 B union (enc uses all; dec 51200B)
    const int bid = blockIdx.x;

    if (bid < NENC) {
        // ================= encoder branch (verified v4 body) =================
        const int ks  = bid % KSPLIT;
        const int tid = bid / KSPLIT;
        if (tid >= meta[63]) return;
        const int c    = meta[64 + 2 * tid];
        const int row0 = meta[65 + 2 * tid];
        const int cnt  = meta[c];
        const int off  = meta[32 + c];
        const int kbase = ks * KC;

        u16* AsH = smem;                                    // [4096]
        u16* AsL = smem + 4096;                             // [4096]
        u16 (*BsH)[8192] = (u16(*)[8192])(smem + 8192);     // [2][8192]
        u16 (*BsL)[8192] = (u16(*)[8192])(smem + 24576);    // [2][8192]

        const int t = threadIdx.x;
        const int lane = t & 63;
        const int w    = t >> 6;              // wave id 0..7
        const int wr = w >> 2, wc = w & 3;    // wave tile: rows wr*64, cols wc*64
        const int fr = lane & 15, fg = lane >> 4;

        // ---- A staging: thread t -> (row ar, k-octet aq); LDS write linear t*16B
        const int ar = ((t >> 6) << 4) | (t & 15);   // 0..127
        const int aq = (t >> 4) & 3;
        int lr = row0 + ar; if (lr > cnt - 1) lr = cnt - 1;
        const float* xp = x + (size_t)order[off + lr] * DIN + kbase + aq * 8;
        const int aoffs = t * 8;

        // ---- B DMA: wave w copies one 4KB chunk/iter:
        //   waves 0-3 -> H plane, 4-7 -> L; nh = w&1, half = (w>>1)&1
        const u16* gchunk = ((w >> 2) ? WpL : WpH)
                          + (size_t)c * PW_C + (size_t)(w & 1) * PW_NH
                          + (size_t)ks * PW_KS + ((w >> 1) & 1) * 2048 + lane * 8;
        u16* lchunk = ((w >> 2) ? &BsL[0][0] : &BsH[0][0])
                    + (w & 1) * 4096 + ((w >> 1) & 1) * 2048 + lane * 8;

        f32x4 acc[4][4];
#pragma unroll
        for (int i = 0; i < 4; ++i)
#pragma unroll
            for (int j = 0; j < 4; ++j) acc[i][j] = (f32x4){0.f, 0.f, 0.f, 0.f};

        auto cvt_store = [&](float4 a0, float4 a1) {
            float av[8] = {a0.x, a0.y, a0.z, a0.w, a1.x, a1.y, a1.z, a1.w};
            s16x8 vh, vl;
#pragma unroll
            for (int i = 0; i < 8; ++i) {
                u16 h, l; f2bf2(av[i], h, l);
                vh[i] = (short)h; vl[i] = (short)l;
            }
            *(s16x8*)&AsH[aoffs] = vh;
            *(s16x8*)&AsL[aoffs] = vl;
        };

        const int arb = fg * 128 + fr * 8;                            // A frag base
        const int brb = (wc >> 1) * 4096 + (wc & 1) * 2048 + arb;     // B frag base (within buf)

        float4 sa0, sa1, sb0, sb1;

        // ---- prologue: pa(0); B(0)->buf0; cvt A(0); pa(1); B(1)->buf1
        sa0 = *(const float4*)xp;
        sa1 = *(const float4*)(xp + 4);
        __builtin_amdgcn_sched_barrier(0);
#pragma unroll
        for (int i = 0; i < 4; ++i) gl16(gchunk + i * 512, lchunk + i * 512);
        __builtin_amdgcn_sched_barrier(0);
        asm volatile("s_waitcnt vmcnt(4)" ::: "memory");   // pa(0) done, B(0) in flight
        cvt_store(sa0, sa1);
        __builtin_amdgcn_sched_barrier(0);
        sb0 = *(const float4*)(xp + 32);
        sb1 = *(const float4*)(xp + 36);
        __builtin_amdgcn_sched_barrier(0);
#pragma unroll
        for (int i = 0; i < 4; ++i) gl16(gchunk + PW_IT + i * 512, lchunk + 8192 + i * 512);
        __builtin_amdgcn_sched_barrier(0);

        for (int itp = 0; itp < NIT; itp += 2) {
            ENC_STEP(itp,     0, sa0, sa1, sb0, sb1);
            ENC_STEP(itp + 1, 1, sb0, sb1, sa0, sa1);
        }

        float* zp = zpart + (size_t)ks * NB * DD;
#pragma unroll
        for (int mt = 0; mt < 4; ++mt) {
#pragma unroll
            for (int r = 0; r < 4; ++r) {
                int lrow = row0 + wr * 64 + mt * 16 + fg * 4 + r;
                if (lrow < cnt) {
                    int gb = order[off + lrow];
                    float* dst = zp + (size_t)gb * DD + wc * 64 + fr;
#pragma unroll
                    for (int ct = 0; ct < 4; ++ct)
                        dst[ct * 16] = acc[mt][ct][r];
                }
            }
        }
        return;
    }

    // ================= decoder branch (512-thread re-index of k_dec) =================
    {
        const int bid2 = bid - NENC;          // 0..95
        const int col0 = (bid2 % 12) * 256;
        const int m0   = (bid2 / 12) * 64;

        u16* AsH = smem;                      // [64*40] = 2560
        u16* AsL = smem + 2560;               // 2560
        u16* BsH = smem + 5120;               // [256*40] = 10240
        u16* BsL = smem + 15360;              // 10240 (ends 25600 u16 = 51200 B)

        const int t = threadIdx.x;            // 0..511
        const int lane = t & 63;
        const int w8  = t >> 6;               // 0..7
        const int wr = w8 >> 2, wc = w8 & 3;  // wave tile: rows wr*32, cols wc*64

        const int ar = t >> 3, aq = t & 7;    // A: row ar(0..63), 4-float granule aq
        const float* ap = cb + (size_t)(m0 + ar) * DD + aq * 4;
        const int bc = t >> 1, bh = t & 1;    // B: col bc(0..255), k-half bh
        const u16* wH0 = dWtH + (size_t)(col0 + bc) * DD + bh * 16;
        const u16* wL0 = dWtL + (size_t)(col0 + bc) * DD + bh * 16;

        f32x4 acc[2][4];
#pragma unroll
        for (int i = 0; i < 2; ++i)
#pragma unroll
            for (int j = 0; j < 4; ++j) acc[i][j] = (f32x4){0.f, 0.f, 0.f, 0.f};

        const int fr = lane & 15, fg = lane >> 4;
        const int aoff = fg * 8;
        const int awr = ar * 40 + aq * 4;
        const int bw0 = bc * 40 + bh * 16;

        float4 pa0 = *(const float4*)(ap);
        s16x8 ph0 = *(const s16x8*)(wH0);
        s16x8 ph1 = *(const s16x8*)(wH0 + 8);
        s16x8 pl0 = *(const s16x8*)(wL0);
        s16x8 pl1 = *(const s16x8*)(wL0 + 8);

        for (int it = 0; it < DD / 32; ++it) {
            {
                float av[4] = {pa0.x, pa0.y, pa0.z, pa0.w};
                s16x4 vh, vl;
#pragma unroll
                for (int i = 0; i < 4; ++i) {
                    u16 h, l; f2bf2(av[i], h, l);
                    vh[i] = (short)h; vl[i] = (short)l;
                }
                *(s16x4*)&AsH[awr] = vh;
                *(s16x4*)&AsL[awr] = vl;
                *(s16x8*)&BsH[bw0]     = ph0;
                *(s16x8*)&BsH[bw0 + 8] = ph1;
                *(s16x8*)&BsL[bw0]     = pl0;
                *(s16x8*)&BsL[bw0 + 8] = pl1;
            }
            __syncthreads();
            if (it + 1 < DD / 32) {
                const int k0 = (it + 1) * 32;
                pa0 = *(const float4*)(ap + k0);
                ph0 = *(const s16x8*)(wH0 + k0);
                ph1 = *(const s16x8*)(wH0 + k0 + 8);
                pl0 = *(const s16x8*)(wL0 + k0);
                pl1 = *(const s16x8*)(wL0 + k0 + 8);
            }
            s16x8 aH0 = *(const s16x8*)&AsH[(wr * 32 + fr) * 40 + aoff];
            s16x8 aH1 = *(const s16x8*)&AsH[(wr * 32 + 16 + fr) * 40 + aoff];
            s16x8 aL0 = *(const s16x8*)&AsL[(wr * 32 + fr) * 40 + aoff];
            s16x8 aL1 = *(const s16x8*)&AsL[(wr * 32 + 16 + fr) * 40 + aoff];
#pragma unroll
            for (int nt = 0; nt < 4; ++nt) {
                const int bcol = wc * 64 + nt * 16 + fr;
                s16x8 bH = *(const s16x8*)&BsH[bcol * 40 + aoff];
                s16x8 bL = *(const s16x8*)&BsL[bcol * 40 + aoff];
                acc[0][nt] = __builtin_amdgcn_mfma_f32_16x16x32_bf16(aH0, bH, acc[0][nt], 0, 0, 0);
                acc[0][nt] = __builtin_amdgcn_mfma_f32_16x16x32_bf16(aL0, bH, acc[0][nt], 0, 0, 0);
                acc[0][nt] = __builtin_amdgcn_mfma_f32_16x16x32_bf16(aH0, bL, acc[0][nt], 0, 0, 0);
                acc[1][nt] = __builtin_amdgcn_mfma_f32_16x16x32_bf16(aH1, bH, acc[1][nt], 0, 0, 0);
                acc[1][nt] = __builtin_amdgcn_mfma_f32_16x16x32_bf16(aL1, bH, acc[1][nt], 0, 0, 0);
                acc[1][nt] = __builtin_amdgcn_mfma_f32_16x16x32_bf16(aH1, bL, acc[1][nt], 0, 0, 0);
            }
            __syncthreads();
        }

#pragma unroll
        for (int mt = 0; mt < 2; ++mt) {
#pragma unroll
            for (int r = 0; r < 4; ++r) {
                int grow = m0 + wr * 32 + mt * 16 + fg * 4 + r;
                float* dst = dcb + (size_t)grow * DIN + col0 + wc * 64 + fr;
#pragma unroll
                for (int nt = 0; nt < 4; ++nt)
                    dst[nt * 16] = acc[mt][nt][r] + db[col0 + wc * 64 + nt * 16 + fr];
            }
        }
    }
}

// ---------------- VQ scores (k_zred fused in: z recomputed from zpart) ----------------
// z slice computed per block with EXACT zred add order (encB then ks 0..5,
// same 4-col granules) -> bitwise identical z -> identical argmin. zn computed
// here too (different summation order than old zred: loss shifts ~1e-7 only;
// all 4 q-blocks write identical zn bits - benign race).
__global__ __launch_bounds__(256) void k_vq(
    const float* __restrict__ zpart, const float* __restrict__ encB,
    const int* __restrict__ label, const float* __restrict__ cbt,
    const float* __restrict__ cbn, float* __restrict__ vmin,
    int* __restrict__ vidx, float* __restrict__ zn)
{
    const int sg = blockIdx.x >> 2;
    const int q  = blockIdx.x & 3;
    const int b0 = sg * 32;
    const int code0 = q * 128;

    __shared__ float As[32][36];
    __shared__ float Bs[32][132];

    const int t = threadIdx.x;
    const int tx = t & 31, ty = t >> 5;

    const int ar = t >> 3, akq = t & 7;
    const float* zpb = zpart + (size_t)(b0 + ar) * DD + akq * 4;
    const float* ebp = encB + (size_t)label[b0 + ar] * DD + akq * 4;
    const int bkk = t >> 3, bcq = t & 7;
    const float* cp = cbt + (size_t)bkk * KCB + code0 + bcq * 16;

    auto loadz = [&](int it) -> float4 {
        float4 s = *(const float4*)(ebp + it * 32);
#pragma unroll
        for (int ks = 0; ks < KSPLIT; ++ks) {
            float4 v = *(const float4*)(zpb + (size_t)ks * NB * DD + it * 32);
            s.x += v.x; s.y += v.y; s.z += v.z; s.w += v.w;
        }
        return s;
    };

    float acc[4][4];
#pragma unroll
    for (int i = 0; i < 4; ++i)
#pragma unroll
        for (int j = 0; j < 4; ++j) acc[i][j] = 0.f;

    float sqa = 0.f;
    float4 pa  = loadz(0);
    float4 pb0 = *(const float4*)(cp);
    float4 pb1 = *(const float4*)(cp + 4);
    float4 pb2 = *(const float4*)(cp + 8);
    float4 pb3 = *(const float4*)(cp + 12);

    for (int it = 0; it < DD / 32; ++it) {
        As[akq * 4 + 0][ar] = pa.x;
        As[akq * 4 + 1][ar] = pa.y;
        As[akq * 4 + 2][ar] = pa.z;
        As[akq * 4 + 3][ar] = pa.w;
        sqa = fmaf(pa.x, pa.x, fmaf(pa.y, pa.y, fmaf(pa.z, pa.z, fmaf(pa.w, pa.w, sqa))));
        *(float4*)&Bs[bkk][bcq * 16]      = pb0;
        *(float4*)&Bs[bkk][bcq * 16 + 4]  = pb1;
        *(float4*)&Bs[bkk][bcq * 16 + 8]  = pb2;
        *(float4*)&Bs[bkk][bcq * 16 + 12] = pb3;
        __syncthreads();
        if (it + 1 < DD / 32) {
            const float* cpn = cp + (size_t)(it + 1) * 32 * KCB;
            pa  = loadz(it + 1);
            pb0 = *(const float4*)(cpn);
            pb1 = *(const float4*)(cpn + 4);
            pb2 = *(const float4*)(cpn + 8);
            pb3 = *(const float4*)(cpn + 12);
        }
#pragma unroll
        for (int kk = 0; kk < 32; ++kk) {
            float4 a4 = *(const float4*)&As[kk][ty * 4];
            float4 b4 = *(const float4*)&Bs[kk][tx * 4];
            float am[4] = {a4.x, a4.y, a4.z, a4.w};
            float bn[4] = {b4.x, b4.y, b4.z, b4.w};
#pragma unroll
            for (int i = 0; i < 4; ++i)
#pragma unroll
                for (int j = 0; j < 4; ++j)
                    acc[i][j] = fmaf(am[i], bn[j], acc[i][j]);
        }
        __syncthreads();
    }

    // zn: reduce the per-thread 32-col partials across the 8 lanes of each row
#pragma unroll
    for (int o = 4; o > 0; o >>= 1) sqa += __shfl_down(sqa, o, 8);
    if ((t & 7) == 0) zn[b0 + ar] = sqa;

    float4 cn4 = *(const float4*)&cbn[code0 + tx * 4];
    float cnv[4] = {cn4.x, cn4.y, cn4.z, cn4.w};
#pragma unroll
    for (int i = 0; i < 4; ++i) {
        float m = cnv[0] - 2.f * acc[i][0];
        int bi = code0 + tx * 4;
#pragma unroll
        for (int j = 1; j < 4; ++j) {
            float sc = cnv[j] - 2.f * acc[i][j];
            if (sc < m) { m = sc; bi = code0 + tx * 4 + j; }
        }
#pragma unroll
        for (int mask = 1; mask <= 16; mask <<= 1) {
            float om = __shfl_xor(m, mask, 64);
            int   oi = __shfl_xor(bi, mask, 64);
            bool lowerSelf = (tx & mask) == 0;
            float lm = lowerSelf ? m : om;
            int   li = lowerSelf ? bi : oi;
            float hm = lowerSelf ? om : m;
            int   hi2 = lowerSelf ? oi : bi;
            if (hm < lm) { m = hm; bi = hi2; } else { m = lm; bi = li; }
        }
        if (tx == 0) {
            vmin[(size_t)(b0 + ty * 4 + i) * 4 + q] = m;
            vidx[(size_t)(b0 + ty * 4 + i) * 4 + q] = bi;
        }
    }
}

// ---------------- gather + SSE partials + last-block final reduction ----------------
__global__ __launch_bounds__(256) void k_gather(
    const float* __restrict__ dcb, const float* __restrict__ vmin, const int* __restrict__ vidx,
    const float* __restrict__ zn, const float* __restrict__ img,
    float* __restrict__ out1, float* __restrict__ ssep, float* __restrict__ lo,
    const int* __restrict__ label, int* meta, float* __restrict__ out0)
{
    const int b = blockIdx.x;
    // inline quarter merge (identical order/tie-break to old k_vqm)
    float m = vmin[(size_t)b * 4]; int k = vidx[(size_t)b * 4];
#pragma unroll
    for (int q = 1; q < 4; ++q) {
        float v = vmin[(size_t)b * 4 + q];
        if (v < m) { m = v; k = vidx[(size_t)b * 4 + q]; }
    }
    if (threadIdx.x == 0) lo[b] = (zn[b] + m) * (1.25f / 256.f);

    const float* src = dcb + (size_t)k * DIN;
    const float* im  = img + (size_t)b * DIN;
    float* o = out1 + (size_t)b * DIN;   // out1 = d_out + 1
    const float4* s4 = (const float4*)src;
    const float4* i4 = (const float4*)im;

    float accv = 0.f;
#pragma unroll
    for (int j = 0; j < 3; ++j) {
        int i = threadIdx.x + j * 256;
        float4 v = s4[i], w = i4[i];
        float dx = v.x - w.x, dy = v.y - w.y, dz = v.z - w.z, dw = v.w - w.w;
        accv = fmaf(dx, dx, fmaf(dy, dy, fmaf(dz, dz, fmaf(dw, dw, accv))));
    }
#pragma unroll
    for (int j = 0; j < 3; ++j) {
        int i = threadIdx.x + j * 256;
        if (i < DIN / 4 - 1) {
            float4 a = s4[i], b2 = s4[i + 1];
            float4 ov = {a.w, b2.x, b2.y, b2.z};
            *(float4*)(o + 3 + 4 * i) = ov;
        }
    }
    if (threadIdx.x == 0) {
        o[0] = src[0]; o[1] = src[1]; o[2] = src[2];
        o[DIN - 1] = src[DIN - 1];
    }

    __shared__ float red[256];
    red[threadIdx.x] = accv;
    __syncthreads();
#pragma unroll
    for (int st = 128; st > 0; st >>= 1) {
        if (threadIdx.x < st) red[threadIdx.x] += red[threadIdx.x + st];
        __syncthreads();
    }
    if (threadIdx.x == 0) ssep[b] = red[0];

    // ---- last-block final reduction (replaces k_final) ----
    __shared__ int lastFlag;
    __threadfence();                       // release: ssep/lo visible device-wide
    __syncthreads();
    if (threadIdx.x == 0) {
        int p = atomicAdd(&meta[61], 1);   // device-scope counter (zeroed by k_wtp)
        lastFlag = (p == (int)gridDim.x - 1) ? 1 : 0;
    }
    __syncthreads();
    if (!lastFlag) return;
    __threadfence();                       // acquire

    const int t = threadIdx.x;
    __shared__ float part[4][12];          // 4 waves x (sse + 10 class sums)

    float se = 0.f;
    float la[NC];
#pragma unroll
    for (int c = 0; c < NC; ++c) la[c] = 0.f;
    for (int bb = t; bb < NB; bb += 256) {
        se += ssep[bb];
        int c2 = label[bb]; float v = lo[bb];
#pragma unroll
        for (int cc = 0; cc < NC; ++cc) la[cc] += (cc == c2) ? v : 0.f;
    }

#pragma unroll
    for (int o2 = 32; o2 > 0; o2 >>= 1) se += __shfl_down(se, o2, 64);
#pragma unroll
    for (int cc = 0; cc < NC; ++cc) {
#pragma unroll
        for (int o2 = 32; o2 > 0; o2 >>= 1) la[cc] += __shfl_down(la[cc], o2, 64);
    }
    if ((t & 63) == 0) {
        const int wv = t >> 6;
        part[wv][0] = se;
#pragma unroll
        for (int cc = 0; cc < NC; ++cc) part[wv][1 + cc] = la[cc];
    }
    __syncthreads();

    if (t == 0) {
        float sse = part[0][0] + part[1][0] + part[2][0] + part[3][0];
        float quant = 0.f, nact = 0.f;
        for (int cc = 0; cc < NC; ++cc) {
            float cs = part[0][1 + cc] + part[1][1 + cc] + part[2][1 + cc] + part[3][1 + cc];
            int cnt = meta[cc];
            if (cnt > 0) { quant += cs / (float)cnt; nact += 1.f; }
        }
        if (nact < 1.f) nact = 1.f;
        quant /= nact;
        out0[0] = sse / (float)(NB * DIN) + quant;
    }
}

extern "C" void kernel_launch(void* const* d_in, const int* in_sizes, int n_in,
                              void* d_out, int out_size, void* d_ws, size_t ws_size,
                              hipStream_t stream)
{
    const float* img   = (const float*)d_in[0];
    const int*   label = (const int*)d_in[1];
    const float* encW  = (const float*)d_in[2];
    const float* encB  = (const float*)d_in[3];
    const float* cb    = (const float*)d_in[4];
    const float* dW    = (const float*)d_in[5];
    const float* db    = (const float*)d_in[6];
    float* out = (float*)d_out;

    char* w = (char*)d_ws;
    float* zpart = (float*)(w);                       // 25,165,824 (6*4096*256*4)
    float* dcb   = (float*)(w + 25165824);            // 6,291,456 (512*3072*4)
    u16*   WtH   = (u16*)  (w + 37748736);            // 15,728,640 (packed)
    u16*   WtL   = (u16*)  (w + 53477376);            // 15,728,640 (packed)
    u16*   dWtH  = (u16*)  (w + 69206016);            // 1,572,864
    u16*   dWtL  = (u16*)  (w + 70778880);            // 1,572,864
    float* vmin  = (float*)(w + 72351744);            // 65,536
    int*   vidx  = (int*)  (w + 72417280);            // 65,536
    float* zn    = (float*)(w + 72482816);            // 16,384
    float* lo    = (float*)(w + 72499200);            // 16,384
    float* ssep  = (float*)(w + 72515584);            // 16,384
    int*   order = (int*)  (w + 72548352);            // 16,384
    int*   meta  = (int*)  (w + 72564736);            // 4,096 (counts/offsets/tilemap/counter)
    float* cbn   = (float*)(w + 72568832);            // 2,048
    float* cbt   = (float*)(w + 72570880);            // 524,288 (256 x 512 f32)

    hipLaunchKernelGGL(k_wtp,    dim3(2147),        dim3(256), 0, stream,
                       label, cb, encW, dW, meta, order, cbn, WtH, WtL, dWtH, dWtL, cbt);
    hipLaunchKernelGGL(k_encdec, dim3(NENC + NDEC), dim3(512), 0, stream,
                       img, WtH, WtL, order, meta, zpart, cb, dWtH, dWtL, db, dcb);
    hipLaunchKernelGGL(k_vq,     dim3(512),         dim3(256), 0, stream,
                       zpart, encB, label, cbt, cbn, vmin, vidx, zn);
    hipLaunchKernelGGL(k_gather, dim3(4096),        dim3(256), 0, stream,
                       dcb, vmin, vidx, zn, img, out + 1, ssep, lo, label, meta, out);
}

// Round 11
// 123.418 us; speedup vs baseline: 4.3640x; 4.3640x over previous
//
#include <hip/hip_runtime.h>
#include <hip/hip_bf16.h>
#include <stddef.h>
#include <stdint.h>

#define NB   4096
#define NC   10
#define DIN  3072
#define DD   256
#define KCB  512
#define KSPLIT 6
#define KC   (DIN / KSPLIT)   /* 512 */
#define TM   128
#define TGRID 42              /* max tiles: sum ceil(cnt/128) <= 32+10 = 42 */
#define NIT  (KC / 32)        /* 16 */
#define NENC (TGRID * KSPLIT) /* 252 enc blocks */
#define NDEC 96               /* 12 col-tiles x 8 row-tiles */

/* packed encW strides (u16 elems): [c][nh 2][ks 6][it 16][cg 8][fg 4][fr 16][8] */
#define PW_C  786432
#define PW_NH 393216
#define PW_KS 65536
#define PW_IT 4096

typedef unsigned short u16;
typedef short s16x8 __attribute__((ext_vector_type(8)));
typedef short s16x4 __attribute__((ext_vector_type(4)));
typedef float f32x4 __attribute__((ext_vector_type(4)));

// f32 -> (hi bf16, lo bf16), both round-to-nearest-even
__device__ inline void f2bf2(float f, u16& h, u16& l) {
    unsigned uf = __builtin_bit_cast(unsigned, f);
    unsigned uh = (uf + 0x7FFFu + ((uf >> 16) & 1u)) >> 16;
    h = (u16)uh;
    float fh = __builtin_bit_cast(float, uh << 16);
    float r = f - fh;
    unsigned ur = __builtin_bit_cast(unsigned, r);
    l = (u16)((ur + 0x7FFFu + ((ur >> 16) & 1u)) >> 16);
}

// async global->LDS DMA, 16B per lane (dest = uniform base + lane*16)
__device__ __forceinline__ void gl16(const u16* g, u16* l) {
    __builtin_amdgcn_global_load_lds(
        (const __attribute__((address_space(1))) unsigned int*)(uintptr_t)g,
        (__attribute__((address_space(3))) unsigned int*)(unsigned int)(uintptr_t)l,
        16, 0, 0);
}

// ---------------- fused prologue ----------------
// blk 0: binning + tilemap; blk 1,2: codebook norms; blk 3..1922: encW pack;
// blk 1923..2114: dW transpose+split; blk 2115..2146: cb f32 transpose
__global__ __launch_bounds__(256) void k_wtp(
    const int* __restrict__ label, const float* __restrict__ cb,
    const float* __restrict__ encW, const float* __restrict__ dW,
    int* __restrict__ meta, int* __restrict__ order, float* __restrict__ cbn,
    u16* __restrict__ WtH, u16* __restrict__ WtL,
    u16* __restrict__ dWtH, u16* __restrict__ dWtL, float* __restrict__ cbt)
{
    const int t = threadIdx.x;
    const int bid = blockIdx.x;
    if (bid == 0) {
        __shared__ int cnt_s[NC], cur_s[NC], off_s[NC];
        if (t < NC) { cnt_s[t] = 0; cur_s[t] = 0; }
        __syncthreads();
        for (int b = t; b < NB; b += 256) atomicAdd(&cnt_s[label[b]], 1);
        __syncthreads();
        if (t == 0) {
            int o = 0;
            for (int c = 0; c < NC; ++c) {
                off_s[c] = o; meta[c] = cnt_s[c]; meta[32 + c] = o; o += cnt_s[c];
            }
            meta[32 + NC] = o;
            int ntl = 0;
            for (int c = 0; c < NC; ++c)
                for (int r0 = 0; r0 < cnt_s[c]; r0 += TM) {
                    meta[64 + 2 * ntl] = c; meta[65 + 2 * ntl] = r0; ++ntl;
                }
            meta[63] = ntl;
        }
        __syncthreads();
        for (int b = t; b < NB; b += 256) {
            int c = label[b];
            int p = atomicAdd(&cur_s[c], 1);
            order[off_s[c] + p] = b;
        }
        return;
    }
    if (bid <= 2) {
        int k = (bid - 1) * 256 + t;
        if (k < KCB) {
            const float* r = cb + (size_t)k * DD;
            float a = 0.f;
#pragma unroll 4
            for (int i = 0; i < 64; ++i) {
                float4 v = *(const float4*)(r + i * 4);
                a = fmaf(v.x, v.x, fmaf(v.y, v.y, fmaf(v.z, v.z, fmaf(v.w, v.w, a))));
            }
            cbn[k] = a;
        }
        return;
    }
    // ---- transpose machinery (64x64 tiles) ----
    const int wb = bid - 3;
    const float* src; int lsrc, ldst, k0, n0;
    u16 *dH = nullptr, *dL = nullptr; float* fdst = nullptr;
    int encw_c = -1;
    if (wb < 1920) {
        int c = wb / 192, rem = wb % 192;
        int kt = rem >> 2, nt = rem & 3;
        k0 = kt * 64; n0 = nt * 64;
        src = encW + (size_t)c * DIN * DD;  lsrc = DD;
        encw_c = c; ldst = 0;
    } else if (wb < 2112) {
        int rem = wb - 1920;
        int kt = rem / 48, nt = rem % 48;
        k0 = kt * 64; n0 = nt * 64;
        src = dW; lsrc = DIN;
        dH = dWtH; dL = dWtL; ldst = DD;
    } else {
        int rem = wb - 2112;          // cb: src rows = codes (512), cols = k (256)
        int kt = rem >> 2, nt = rem & 3;
        k0 = kt * 64; n0 = nt * 64;
        src = cb; lsrc = DD;
        fdst = cbt; ldst = KCB;
    }
    __shared__ float tile[64][65];
    const int trow = t >> 4, tc4 = t & 15;
#pragma unroll
    for (int j = 0; j < 4; ++j) {
        int kk = trow * 4 + j;
        float4 v = *(const float4*)&src[(size_t)(k0 + kk) * lsrc + n0 + tc4 * 4];
        tile[kk][tc4 * 4 + 0] = v.x; tile[kk][tc4 * 4 + 1] = v.y;
        tile[kk][tc4 * 4 + 2] = v.z; tile[kk][tc4 * 4 + 3] = v.w;
    }
    __syncthreads();
    const int n = n0 + (t >> 2), q = t & 3;
    if (fdst) {
#pragma unroll
        for (int j = 0; j < 4; ++j) {
            float4 o = {tile[q * 16 + 4 * j + 0][n - n0], tile[q * 16 + 4 * j + 1][n - n0],
                        tile[q * 16 + 4 * j + 2][n - n0], tile[q * 16 + 4 * j + 3][n - n0]};
            *(float4*)&fdst[(size_t)n * ldst + k0 + q * 16 + 4 * j] = o;
        }
        return;
    }
    s16x8 vh0, vh1, vl0, vl1;
#pragma unroll
    for (int i = 0; i < 8; ++i) {
        u16 h, l;
        f2bf2(tile[q * 16 + i][n - n0], h, l);
        vh0[i] = (short)h; vl0[i] = (short)l;
    }
#pragma unroll
    for (int i = 0; i < 8; ++i) {
        u16 h, l;
        f2bf2(tile[q * 16 + 8 + i][n - n0], h, l);
        vh1[i] = (short)h; vl1[i] = (short)l;
    }
    if (encw_c >= 0) {
        // packed store: [c][nh][ks][it][cg][fg][fr][8]
        const int nh = n >> 7, cg = (n & 127) >> 4, fr2 = n & 15;
        const size_t nbase = (size_t)encw_c * PW_C + (size_t)nh * PW_NH
                           + (size_t)cg * 512 + (size_t)fr2 * 8;
        int ko = (k0 >> 3) + 2 * q;
        {
            int ks2 = ko >> 6, r2 = ko & 63, it2 = r2 >> 2, fg2 = r2 & 3;
            size_t o = nbase + (size_t)ks2 * PW_KS + (size_t)it2 * PW_IT + (size_t)fg2 * 128;
            *(s16x8*)&WtH[o] = vh0; *(s16x8*)&WtL[o] = vl0;
        }
        {
            int ko1 = ko + 1;
            int ks2 = ko1 >> 6, r2 = ko1 & 63, it2 = r2 >> 2, fg2 = r2 & 3;
            size_t o = nbase + (size_t)ks2 * PW_KS + (size_t)it2 * PW_IT + (size_t)fg2 * 128;
            *(s16x8*)&WtH[o] = vh1; *(s16x8*)&WtL[o] = vl1;
        }
        return;
    }
    u16* oH = dH + (size_t)n * ldst + k0 + q * 16;
    u16* oL = dL + (size_t)n * ldst + k0 + q * 16;
    *(s16x8*)oH = vh0; *(s16x8*)(oH + 8) = vh1;
    *(s16x8*)oL = vl0; *(s16x8*)(oL + 8) = vl1;
}

// ---------------- fused encoder GEMM (v4, verified) + decoder GEMM ----------------
#define ENC_STEP(IT, PB, L0, L1, C0, C1)                                        \
    {                                                                           \
        if ((IT) + 1 < NIT) { asm volatile("s_waitcnt vmcnt(6)" ::: "memory"); } \
        else                { asm volatile("s_waitcnt vmcnt(0)" ::: "memory"); } \
        asm volatile("s_waitcnt lgkmcnt(0)" ::: "memory");                      \
        __builtin_amdgcn_s_barrier();                                           \
        __builtin_amdgcn_sched_barrier(0);                                      \
        s16x8 aH[4], aL[4], bH[4], bL[4];                                       \
        _Pragma("unroll")                                                       \
        for (int mt = 0; mt < 4; ++mt) {                                        \
            aH[mt] = *(const s16x8*)&AsH[(wr * 4 + mt) * 512 + arb];            \
            aL[mt] = *(const s16x8*)&AsL[(wr * 4 + mt) * 512 + arb];            \
        }                                                                       \
        _Pragma("unroll")                                                       \
        for (int ct = 0; ct < 4; ++ct) {                                        \
            bH[ct] = *(const s16x8*)&BsH[PB][ct * 512 + brb];                   \
            bL[ct] = *(const s16x8*)&BsL[PB][ct * 512 + brb];                   \
        }                                                                       \
        asm volatile("s_waitcnt lgkmcnt(0)" ::: "memory");                      \
        __builtin_amdgcn_sched_barrier(0);                                      \
        __builtin_amdgcn_s_barrier();                                           \
        __builtin_amdgcn_sched_barrier(0);                                      \
        if ((IT) + 2 < NIT) {                                                   \
            L0 = *(const float4*)(xp + ((IT) + 2) * 32);                        \
            L1 = *(const float4*)(xp + ((IT) + 2) * 32 + 4);                    \
            __builtin_amdgcn_sched_barrier(0);                                  \
            const u16* g_ = gchunk + (size_t)((IT) + 2) * PW_IT;                \
            u16* l_ = lchunk + (PB) * 8192;                                     \
            _Pragma("unroll")                                                   \
            for (int i = 0; i < 4; ++i) gl16(g_ + i * 512, l_ + i * 512);       \
            __builtin_amdgcn_sched_barrier(0);                                  \
        }                                                                       \
        __builtin_amdgcn_s_setprio(1);                                          \
        _Pragma("unroll")                                                       \
        for (int ct = 0; ct < 4; ++ct) {                                        \
            _Pragma("unroll")                                                   \
            for (int mt = 0; mt < 4; ++mt) {                                    \
                acc[mt][ct] = __builtin_amdgcn_mfma_f32_16x16x32_bf16(aH[mt], bH[ct], acc[mt][ct], 0, 0, 0); \
                acc[mt][ct] = __builtin_amdgcn_mfma_f32_16x16x32_bf16(aL[mt], bH[ct], acc[mt][ct], 0, 0, 0); \
                acc[mt][ct] = __builtin_amdgcn_mfma_f32_16x16x32_bf16(aH[mt], bL[ct], acc[mt][ct], 0, 0, 0); \
            }                                                                   \
        }                                                                       \
        __builtin_amdgcn_s_setprio(0);                                          \
        if ((IT) + 1 < NIT) {                                                   \
            if ((IT) + 2 < NIT) { asm volatile("s_waitcnt vmcnt(10)" ::: "memory"); } \
            else                { asm volatile("s_waitcnt vmcnt(4)"  ::: "memory"); } \
            cvt_store(C0, C1);                                                  \
        }                                                                       \
    }

__global__ __launch_bounds__(512, 2) void k_encdec(
    const float* __restrict__ x, const u16* __restrict__ WpH, const u16* __restrict__ WpL,
    const int* __restrict__ order, const int* __restrict__ meta, float* __restrict__ zpart,
    const float* __restrict__ cb, const u16* __restrict__ dWtH, const u16* __restrict__ dWtL,
    const float* __restrict__ db, float* __restrict__ dcb)
{
    __shared__ __align__(16) u16 smem[40960];   // 81920 B union (enc uses all; dec 51200B)
    const int bid = blockIdx.x;

    if (bid < NENC) {
        // ================= encoder branch (verified v4 body) =================
        const int ks  = bid % KSPLIT;
        const int tid = bid / KSPLIT;
        if (tid >= meta[63]) return;
        const int c    = meta[64 + 2 * tid];
        const int row0 = meta[65 + 2 * tid];
        const int cnt  = meta[c];
        const int off  = meta[32 + c];
        const int kbase = ks * KC;

        u16* AsH = smem;                                    // [4096]
        u16* AsL = smem + 4096;                             // [4096]
        u16 (*BsH)[8192] = (u16(*)[8192])(smem + 8192);     // [2][8192]
        u16 (*BsL)[8192] = (u16(*)[8192])(smem + 24576);    // [2][8192]

        const int t = threadIdx.x;
        const int lane = t & 63;
        const int w    = t >> 6;              // wave id 0..7
        const int wr = w >> 2, wc = w & 3;    // wave tile: rows wr*64, cols wc*64
        const int fr = lane & 15, fg = lane >> 4;

        // ---- A staging: thread t -> (row ar, k-octet aq); LDS write linear t*16B
        const int ar = ((t >> 6) << 4) | (t & 15);   // 0..127
        const int aq = (t >> 4) & 3;
        int lr = row0 + ar; if (lr > cnt - 1) lr = cnt - 1;
        const float* xp = x + (size_t)order[off + lr] * DIN + kbase + aq * 8;
        const int aoffs = t * 8;

        // ---- B DMA: wave w copies one 4KB chunk/iter:
        //   waves 0-3 -> H plane, 4-7 -> L; nh = w&1, half = (w>>1)&1
        const u16* gchunk = ((w >> 2) ? WpL : WpH)
                          + (size_t)c * PW_C + (size_t)(w & 1) * PW_NH
                          + (size_t)ks * PW_KS + ((w >> 1) & 1) * 2048 + lane * 8;
        u16* lchunk = ((w >> 2) ? &BsL[0][0] : &BsH[0][0])
                    + (w & 1) * 4096 + ((w >> 1) & 1) * 2048 + lane * 8;

        f32x4 acc[4][4];
#pragma unroll
        for (int i = 0; i < 4; ++i)
#pragma unroll
            for (int j = 0; j < 4; ++j) acc[i][j] = (f32x4){0.f, 0.f, 0.f, 0.f};

        auto cvt_store = [&](float4 a0, float4 a1) {
            float av[8] = {a0.x, a0.y, a0.z, a0.w, a1.x, a1.y, a1.z, a1.w};
            s16x8 vh, vl;
#pragma unroll
            for (int i = 0; i < 8; ++i) {
                u16 h, l; f2bf2(av[i], h, l);
                vh[i] = (short)h; vl[i] = (short)l;
            }
            *(s16x8*)&AsH[aoffs] = vh;
            *(s16x8*)&AsL[aoffs] = vl;
        };

        const int arb = fg * 128 + fr * 8;                            // A frag base
        const int brb = (wc >> 1) * 4096 + (wc & 1) * 2048 + arb;     // B frag base (within buf)

        float4 sa0, sa1, sb0, sb1;

        // ---- prologue: pa(0); B(0)->buf0; cvt A(0); pa(1); B(1)->buf1
        sa0 = *(const float4*)xp;
        sa1 = *(const float4*)(xp + 4);
        __builtin_amdgcn_sched_barrier(0);
#pragma unroll
        for (int i = 0; i < 4; ++i) gl16(gchunk + i * 512, lchunk + i * 512);
        __builtin_amdgcn_sched_barrier(0);
        asm volatile("s_waitcnt vmcnt(4)" ::: "memory");   // pa(0) done, B(0) in flight
        cvt_store(sa0, sa1);
        __builtin_amdgcn_sched_barrier(0);
        sb0 = *(const float4*)(xp + 32);
        sb1 = *(const float4*)(xp + 36);
        __builtin_amdgcn_sched_barrier(0);
#pragma unroll
        for (int i = 0; i < 4; ++i) gl16(gchunk + PW_IT + i * 512, lchunk + 8192 + i * 512);
        __builtin_amdgcn_sched_barrier(0);

        for (int itp = 0; itp < NIT; itp += 2) {
            ENC_STEP(itp,     0, sa0, sa1, sb0, sb1);
            ENC_STEP(itp + 1, 1, sb0, sb1, sa0, sa1);
        }

        float* zp = zpart + (size_t)ks * NB * DD;
#pragma unroll
        for (int mt = 0; mt < 4; ++mt) {
#pragma unroll
            for (int r = 0; r < 4; ++r) {
                int lrow = row0 + wr * 64 + mt * 16 + fg * 4 + r;
                if (lrow < cnt) {
                    int gb = order[off + lrow];
                    float* dst = zp + (size_t)gb * DD + wc * 64 + fr;
#pragma unroll
                    for (int ct = 0; ct < 4; ++ct)
                        dst[ct * 16] = acc[mt][ct][r];
                }
            }
        }
        return;
    }

    // ================= decoder branch (512-thread re-index of k_dec) =================
    {
        const int bid2 = bid - NENC;          // 0..95
        const int col0 = (bid2 % 12) * 256;
        const int m0   = (bid2 / 12) * 64;

        u16* AsH = smem;                      // [64*40] = 2560
        u16* AsL = smem + 2560;               // 2560
        u16* BsH = smem + 5120;               // [256*40] = 10240
        u16* BsL = smem + 15360;              // 10240 (ends 25600 u16 = 51200 B)

        const int t = threadIdx.x;            // 0..511
        const int lane = t & 63;
        const int w8  = t >> 6;               // 0..7
        const int wr = w8 >> 2, wc = w8 & 3;  // wave tile: rows wr*32, cols wc*64

        const int ar = t >> 3, aq = t & 7;    // A: row ar(0..63), 4-float granule aq
        const float* ap = cb + (size_t)(m0 + ar) * DD + aq * 4;
        const int bc = t >> 1, bh = t & 1;    // B: col bc(0..255), k-half bh
        const u16* wH0 = dWtH + (size_t)(col0 + bc) * DD + bh * 16;
        const u16* wL0 = dWtL + (size_t)(col0 + bc) * DD + bh * 16;

        f32x4 acc[2][4];
#pragma unroll
        for (int i = 0; i < 2; ++i)
#pragma unroll
            for (int j = 0; j < 4; ++j) acc[i][j] = (f32x4){0.f, 0.f, 0.f, 0.f};

        const int fr = lane & 15, fg = lane >> 4;
        const int aoff = fg * 8;
        const int awr = ar * 40 + aq * 4;
        const int bw0 = bc * 40 + bh * 16;

        float4 pa0 = *(const float4*)(ap);
        s16x8 ph0 = *(const s16x8*)(wH0);
        s16x8 ph1 = *(const s16x8*)(wH0 + 8);
        s16x8 pl0 = *(const s16x8*)(wL0);
        s16x8 pl1 = *(const s16x8*)(wL0 + 8);

        for (int it = 0; it < DD / 32; ++it) {
            {
                float av[4] = {pa0.x, pa0.y, pa0.z, pa0.w};
                s16x4 vh, vl;
#pragma unroll
                for (int i = 0; i < 4; ++i) {
                    u16 h, l; f2bf2(av[i], h, l);
                    vh[i] = (short)h; vl[i] = (short)l;
                }
                *(s16x4*)&AsH[awr] = vh;
                *(s16x4*)&AsL[awr] = vl;
                *(s16x8*)&BsH[bw0]     = ph0;
                *(s16x8*)&BsH[bw0 + 8] = ph1;
                *(s16x8*)&BsL[bw0]     = pl0;
                *(s16x8*)&BsL[bw0 + 8] = pl1;
            }
            __syncthreads();
            if (it + 1 < DD / 32) {
                const int k0 = (it + 1) * 32;
                pa0 = *(const float4*)(ap + k0);
                ph0 = *(const s16x8*)(wH0 + k0);
                ph1 = *(const s16x8*)(wH0 + k0 + 8);
                pl0 = *(const s16x8*)(wL0 + k0);
                pl1 = *(const s16x8*)(wL0 + k0 + 8);
            }
            s16x8 aH0 = *(const s16x8*)&AsH[(wr * 32 + fr) * 40 + aoff];
            s16x8 aH1 = *(const s16x8*)&AsH[(wr * 32 + 16 + fr) * 40 + aoff];
            s16x8 aL0 = *(const s16x8*)&AsL[(wr * 32 + fr) * 40 + aoff];
            s16x8 aL1 = *(const s16x8*)&AsL[(wr * 32 + 16 + fr) * 40 + aoff];
#pragma unroll
            for (int nt = 0; nt < 4; ++nt) {
                const int bcol = wc * 64 + nt * 16 + fr;
                s16x8 bH = *(const s16x8*)&BsH[bcol * 40 + aoff];
                s16x8 bL = *(const s16x8*)&BsL[bcol * 40 + aoff];
                acc[0][nt] = __builtin_amdgcn_mfma_f32_16x16x32_bf16(aH0, bH, acc[0][nt], 0, 0, 0);
                acc[0][nt] = __builtin_amdgcn_mfma_f32_16x16x32_bf16(aL0, bH, acc[0][nt], 0, 0, 0);
                acc[0][nt] = __builtin_amdgcn_mfma_f32_16x16x32_bf16(aH0, bL, acc[0][nt], 0, 0, 0);
                acc[1][nt] = __builtin_amdgcn_mfma_f32_16x16x32_bf16(aH1, bH, acc[1][nt], 0, 0, 0);
                acc[1][nt] = __builtin_amdgcn_mfma_f32_16x16x32_bf16(aL1, bH, acc[1][nt], 0, 0, 0);
                acc[1][nt] = __builtin_amdgcn_mfma_f32_16x16x32_bf16(aH1, bL, acc[1][nt], 0, 0, 0);
            }
            __syncthreads();
        }

#pragma unroll
        for (int mt = 0; mt < 2; ++mt) {
#pragma unroll
            for (int r = 0; r < 4; ++r) {
                int grow = m0 + wr * 32 + mt * 16 + fg * 4 + r;
                float* dst = dcb + (size_t)grow * DIN + col0 + wc * 64 + fr;
#pragma unroll
                for (int nt = 0; nt < 4; ++nt)
                    dst[nt * 16] = acc[mt][nt][r] + db[col0 + wc * 64 + nt * 16 + fr];
            }
        }
    }
}

// ---------------- VQ scores (k_zred fused in: z recomputed from zpart) ----------------
// z slice computed per block with EXACT zred add order (encB then ks 0..5,
// same 4-col granules) -> bitwise identical z -> identical argmin. zn computed
// here too (different summation order than old zred: loss shifts ~1e-7 only;
// all 4 q-blocks write identical zn bits - benign race). VERIFIED R10 (passed,
// absmax 0.015625).
__global__ __launch_bounds__(256) void k_vq(
    const float* __restrict__ zpart, const float* __restrict__ encB,
    const int* __restrict__ label, const float* __restrict__ cbt,
    const float* __restrict__ cbn, float* __restrict__ vmin,
    int* __restrict__ vidx, float* __restrict__ zn)
{
    const int sg = blockIdx.x >> 2;
    const int q  = blockIdx.x & 3;
    const int b0 = sg * 32;
    const int code0 = q * 128;

    __shared__ float As[32][36];
    __shared__ float Bs[32][132];

    const int t = threadIdx.x;
    const int tx = t & 31, ty = t >> 5;

    const int ar = t >> 3, akq = t & 7;
    const float* zpb = zpart + (size_t)(b0 + ar) * DD + akq * 4;
    const float* ebp = encB + (size_t)label[b0 + ar] * DD + akq * 4;
    const int bkk = t >> 3, bcq = t & 7;
    const float* cp = cbt + (size_t)bkk * KCB + code0 + bcq * 16;

    auto loadz = [&](int it) -> float4 {
        float4 s = *(const float4*)(ebp + it * 32);
#pragma unroll
        for (int ks = 0; ks < KSPLIT; ++ks) {
            float4 v = *(const float4*)(zpb + (size_t)ks * NB * DD + it * 32);
            s.x += v.x; s.y += v.y; s.z += v.z; s.w += v.w;
        }
        return s;
    };

    float acc[4][4];
#pragma unroll
    for (int i = 0; i < 4; ++i)
#pragma unroll
        for (int j = 0; j < 4; ++j) acc[i][j] = 0.f;

    float sqa = 0.f;
    float4 pa  = loadz(0);
    float4 pb0 = *(const float4*)(cp);
    float4 pb1 = *(const float4*)(cp + 4);
    float4 pb2 = *(const float4*)(cp + 8);
    float4 pb3 = *(const float4*)(cp + 12);

    for (int it = 0; it < DD / 32; ++it) {
        As[akq * 4 + 0][ar] = pa.x;
        As[akq * 4 + 1][ar] = pa.y;
        As[akq * 4 + 2][ar] = pa.z;
        As[akq * 4 + 3][ar] = pa.w;
        sqa = fmaf(pa.x, pa.x, fmaf(pa.y, pa.y, fmaf(pa.z, pa.z, fmaf(pa.w, pa.w, sqa))));
        *(float4*)&Bs[bkk][bcq * 16]      = pb0;
        *(float4*)&Bs[bkk][bcq * 16 + 4]  = pb1;
        *(float4*)&Bs[bkk][bcq * 16 + 8]  = pb2;
        *(float4*)&Bs[bkk][bcq * 16 + 12] = pb3;
        __syncthreads();
        if (it + 1 < DD / 32) {
            const float* cpn = cp + (size_t)(it + 1) * 32 * KCB;
            pa  = loadz(it + 1);
            pb0 = *(const float4*)(cpn);
            pb1 = *(const float4*)(cpn + 4);
            pb2 = *(const float4*)(cpn + 8);
            pb3 = *(const float4*)(cpn + 12);
        }
#pragma unroll
        for (int kk = 0; kk < 32; ++kk) {
            float4 a4 = *(const float4*)&As[kk][ty * 4];
            float4 b4 = *(const float4*)&Bs[kk][tx * 4];
            float am[4] = {a4.x, a4.y, a4.z, a4.w};
            float bn[4] = {b4.x, b4.y, b4.z, b4.w};
#pragma unroll
            for (int i = 0; i < 4; ++i)
#pragma unroll
                for (int j = 0; j < 4; ++j)
                    acc[i][j] = fmaf(am[i], bn[j], acc[i][j]);
        }
        __syncthreads();
    }

    // zn: reduce the per-thread 32-col partials across the 8 lanes of each row
#pragma unroll
    for (int o = 4; o > 0; o >>= 1) sqa += __shfl_down(sqa, o, 8);
    if ((t & 7) == 0) zn[b0 + ar] = sqa;

    float4 cn4 = *(const float4*)&cbn[code0 + tx * 4];
    float cnv[4] = {cn4.x, cn4.y, cn4.z, cn4.w};
#pragma unroll
    for (int i = 0; i < 4; ++i) {
        float m = cnv[0] - 2.f * acc[i][0];
        int bi = code0 + tx * 4;
#pragma unroll
        for (int j = 1; j < 4; ++j) {
            float sc = cnv[j] - 2.f * acc[i][j];
            if (sc < m) { m = sc; bi = code0 + tx * 4 + j; }
        }
#pragma unroll
        for (int mask = 1; mask <= 16; mask <<= 1) {
            float om = __shfl_xor(m, mask, 64);
            int   oi = __shfl_xor(bi, mask, 64);
            bool lowerSelf = (tx & mask) == 0;
            float lm = lowerSelf ? m : om;
            int   li = lowerSelf ? bi : oi;
            float hm = lowerSelf ? om : m;
            int   hi2 = lowerSelf ? oi : bi;
            if (hm < lm) { m = hm; bi = hi2; } else { m = lm; bi = li; }
        }
        if (tx == 0) {
            vmin[(size_t)(b0 + ty * 4 + i) * 4 + q] = m;
            vidx[(size_t)(b0 + ty * 4 + i) * 4 + q] = bi;
        }
    }
}

// ---------------- gather decoded rows + SSE partials (R9-verified, NO fence) ----------------
__global__ __launch_bounds__(256) void k_gather(
    const float* __restrict__ dcb, const float* __restrict__ vmin, const int* __restrict__ vidx,
    const float* __restrict__ zn, const float* __restrict__ img,
    float* __restrict__ out1, float* __restrict__ ssep, float* __restrict__ lo)
{
    const int b = blockIdx.x;
    // inline quarter merge (identical order/tie-break to old k_vqm)
    float m = vmin[(size_t)b * 4]; int k = vidx[(size_t)b * 4];
#pragma unroll
    for (int q = 1; q < 4; ++q) {
        float v = vmin[(size_t)b * 4 + q];
        if (v < m) { m = v; k = vidx[(size_t)b * 4 + q]; }
    }
    if (threadIdx.x == 0) lo[b] = (zn[b] + m) * (1.25f / 256.f);

    const float* src = dcb + (size_t)k * DIN;
    const float* im  = img + (size_t)b * DIN;
    float* o = out1 + (size_t)b * DIN;   // out1 = d_out + 1
    const float4* s4 = (const float4*)src;
    const float4* i4 = (const float4*)im;

    float accv = 0.f;
#pragma unroll
    for (int j = 0; j < 3; ++j) {
        int i = threadIdx.x + j * 256;
        float4 v = s4[i], w = i4[i];
        float dx = v.x - w.x, dy = v.y - w.y, dz = v.z - w.z, dw = v.w - w.w;
        accv = fmaf(dx, dx, fmaf(dy, dy, fmaf(dz, dz, fmaf(dw, dw, accv))));
    }
#pragma unroll
    for (int j = 0; j < 3; ++j) {
        int i = threadIdx.x + j * 256;
        if (i < DIN / 4 - 1) {
            float4 a = s4[i], b2 = s4[i + 1];
            float4 ov = {a.w, b2.x, b2.y, b2.z};
            *(float4*)(o + 3 + 4 * i) = ov;
        }
    }
    if (threadIdx.x == 0) {
        o[0] = src[0]; o[1] = src[1]; o[2] = src[2];
        o[DIN - 1] = src[DIN - 1];
    }

    __shared__ float red[256];
    red[threadIdx.x] = accv;
    __syncthreads();
#pragma unroll
    for (int st = 128; st > 0; st >>= 1) {
        if (threadIdx.x < st) red[threadIdx.x] += red[threadIdx.x + st];
        __syncthreads();
    }
    if (threadIdx.x == 0) ssep[b] = red[0];
}

// ---------------- final deterministic reduction (wave-shuffle, R9-verified) ----------------
__global__ __launch_bounds__(256) void k_final(
    const float* __restrict__ ssep, const float* __restrict__ lo, const int* __restrict__ label,
    const int* __restrict__ meta, float* __restrict__ out)
{
    const int t = threadIdx.x;
    __shared__ float part[4][12];   // 4 waves x (sse + 10 class sums)

    float se = 0.f;
    float la[NC];
#pragma unroll
    for (int c = 0; c < NC; ++c) la[c] = 0.f;
    for (int b = t; b < NB; b += 256) {
        se += ssep[b];
        int c2 = label[b]; float v = lo[b];
#pragma unroll
        for (int cc = 0; cc < NC; ++cc) la[cc] += (cc == c2) ? v : 0.f;
    }

#pragma unroll
    for (int o = 32; o > 0; o >>= 1) se += __shfl_down(se, o, 64);
#pragma unroll
    for (int cc = 0; cc < NC; ++cc) {
#pragma unroll
        for (int o = 32; o > 0; o >>= 1) la[cc] += __shfl_down(la[cc], o, 64);
    }
    if ((t & 63) == 0) {
        const int wv = t >> 6;
        part[wv][0] = se;
#pragma unroll
        for (int cc = 0; cc < NC; ++cc) part[wv][1 + cc] = la[cc];
    }
    __syncthreads();

    if (t == 0) {
        float sse = part[0][0] + part[1][0] + part[2][0] + part[3][0];
        float quant = 0.f, nact = 0.f;
        for (int cc = 0; cc < NC; ++cc) {
            float cs = part[0][1 + cc] + part[1][1 + cc] + part[2][1 + cc] + part[3][1 + cc];
            int cnt = meta[cc];
            if (cnt > 0) { quant += cs / (float)cnt; nact += 1.f; }
        }
        if (nact < 1.f) nact = 1.f;
        quant /= nact;
        out[0] = sse / (float)(NB * DIN) + quant;
    }
}

extern "C" void kernel_launch(void* const* d_in, const int* in_sizes, int n_in,
                              void* d_out, int out_size, void* d_ws, size_t ws_size,
                              hipStream_t stream)
{
    const float* img   = (const float*)d_in[0];
    const int*   label = (const int*)d_in[1];
    const float* encW  = (const float*)d_in[2];
    const float* encB  = (const float*)d_in[3];
    const float* cb    = (const float*)d_in[4];
    const float* dW    = (const float*)d_in[5];
    const float* db    = (const float*)d_in[6];
    float* out = (float*)d_out;

    char* w = (char*)d_ws;
    float* zpart = (float*)(w);                       // 25,165,824 (6*4096*256*4)
    float* dcb   = (float*)(w + 25165824);            // 6,291,456 (512*3072*4)
    u16*   WtH   = (u16*)  (w + 37748736);            // 15,728,640 (packed)
    u16*   WtL   = (u16*)  (w + 53477376);            // 15,728,640 (packed)
    u16*   dWtH  = (u16*)  (w + 69206016);            // 1,572,864
    u16*   dWtL  = (u16*)  (w + 70778880);            // 1,572,864
    float* vmin  = (float*)(w + 72351744);            // 65,536
    int*   vidx  = (int*)  (w + 72417280);            // 65,536
    float* zn    = (float*)(w + 72482816);            // 16,384
    float* lo    = (float*)(w + 72499200);            // 16,384
    float* ssep  = (float*)(w + 72515584);            // 16,384
    int*   order = (int*)  (w + 72548352);            // 16,384
    int*   meta  = (int*)  (w + 72564736);            // 4,096 (counts/offsets/tilemap)
    float* cbn   = (float*)(w + 72568832);            // 2,048
    float* cbt   = (float*)(w + 72570880);            // 524,288 (256 x 512 f32)

    hipLaunchKernelGGL(k_wtp,    dim3(2147),        dim3(256), 0, stream,
                       label, cb, encW, dW, meta, order, cbn, WtH, WtL, dWtH, dWtL, cbt);
    hipLaunchKernelGGL(k_encdec, dim3(NENC + NDEC), dim3(512), 0, stream,
                       img, WtH, WtL, order, meta, zpart, cb, dWtH, dWtL, db, dcb);
    hipLaunchKernelGGL(k_vq,     dim3(512),         dim3(256), 0, stream,
                       zpart, encB, label, cbt, cbn, vmin, vidx, zn);
    hipLaunchKernelGGL(k_gather, dim3(4096),        dim3(256), 0, stream,
                       dcb, vmin, vidx, zn, img, out + 1, ssep, lo);
    hipLaunchKernelGGL(k_final,  dim3(1),           dim3(256), 0, stream, ssep, lo, label, meta, out);
}

// Round 12
// 121.859 us; speedup vs baseline: 4.4198x; 1.0128x over previous
//
#include <hip/hip_runtime.h>
#include <hip/hip_bf16.h>
#include <stddef.h>
#include <stdint.h>

#define NB   4096
#define NC   10
#define DIN  3072
#define DD   256
#define KCB  512
#define KSPLIT 6
#define KC   (DIN / KSPLIT)   /* 512 */
#define TM   128
#define TGRID 42              /* max tiles: sum ceil(cnt/128) <= 32+10 = 42 */
#define NIT  (KC / 32)        /* 16 */
#define NENC (TGRID * KSPLIT) /* 252 enc blocks */
#define NDEC 192              /* 12 col-tiles x 16 row-tiles (32 rows each) */

/* packed encW strides (u16 elems): [c][nh 2][ks 6][it 16][cg 8][fg 4][fr 16][8] */
#define PW_C  786432
#define PW_NH 393216
#define PW_KS 65536
#define PW_IT 4096

typedef unsigned short u16;
typedef short s16x8 __attribute__((ext_vector_type(8)));
typedef short s16x2 __attribute__((ext_vector_type(2)));
typedef float f32x4 __attribute__((ext_vector_type(4)));

// f32 -> (hi bf16, lo bf16), both round-to-nearest-even
__device__ inline void f2bf2(float f, u16& h, u16& l) {
    unsigned uf = __builtin_bit_cast(unsigned, f);
    unsigned uh = (uf + 0x7FFFu + ((uf >> 16) & 1u)) >> 16;
    h = (u16)uh;
    float fh = __builtin_bit_cast(float, uh << 16);
    float r = f - fh;
    unsigned ur = __builtin_bit_cast(unsigned, r);
    l = (u16)((ur + 0x7FFFu + ((ur >> 16) & 1u)) >> 16);
}

// async global->LDS DMA, 16B per lane (dest = uniform base + lane*16)
__device__ __forceinline__ void gl16(const u16* g, u16* l) {
    __builtin_amdgcn_global_load_lds(
        (const __attribute__((address_space(1))) unsigned int*)(uintptr_t)g,
        (__attribute__((address_space(3))) unsigned int*)(unsigned int)(uintptr_t)l,
        16, 0, 0);
}

// ---------------- fused prologue ----------------
// blk 0: binning + tilemap; blk 1,2: codebook norms; blk 3..1922: encW pack;
// blk 1923..2114: dW transpose+split; blk 2115..2146: cb f32 transpose
__global__ __launch_bounds__(256) void k_wtp(
    const int* __restrict__ label, const float* __restrict__ cb,
    const float* __restrict__ encW, const float* __restrict__ dW,
    int* __restrict__ meta, int* __restrict__ order, float* __restrict__ cbn,
    u16* __restrict__ WtH, u16* __restrict__ WtL,
    u16* __restrict__ dWtH, u16* __restrict__ dWtL, float* __restrict__ cbt)
{
    const int t = threadIdx.x;
    const int bid = blockIdx.x;
    if (bid == 0) {
        __shared__ int cnt_s[NC], cur_s[NC], off_s[NC];
        if (t < NC) { cnt_s[t] = 0; cur_s[t] = 0; }
        __syncthreads();
        for (int b = t; b < NB; b += 256) atomicAdd(&cnt_s[label[b]], 1);
        __syncthreads();
        if (t == 0) {
            int o = 0;
            for (int c = 0; c < NC; ++c) {
                off_s[c] = o; meta[c] = cnt_s[c]; meta[32 + c] = o; o += cnt_s[c];
            }
            meta[32 + NC] = o;
            int ntl = 0;
            for (int c = 0; c < NC; ++c)
                for (int r0 = 0; r0 < cnt_s[c]; r0 += TM) {
                    meta[64 + 2 * ntl] = c; meta[65 + 2 * ntl] = r0; ++ntl;
                }
            meta[63] = ntl;
        }
        __syncthreads();
        for (int b = t; b < NB; b += 256) {
            int c = label[b];
            int p = atomicAdd(&cur_s[c], 1);
            order[off_s[c] + p] = b;
        }
        return;
    }
    if (bid <= 2) {
        int k = (bid - 1) * 256 + t;
        if (k < KCB) {
            const float* r = cb + (size_t)k * DD;
            float a = 0.f;
#pragma unroll 4
            for (int i = 0; i < 64; ++i) {
                float4 v = *(const float4*)(r + i * 4);
                a = fmaf(v.x, v.x, fmaf(v.y, v.y, fmaf(v.z, v.z, fmaf(v.w, v.w, a))));
            }
            cbn[k] = a;
        }
        return;
    }
    // ---- transpose machinery (64x64 tiles) ----
    const int wb = bid - 3;
    const float* src; int lsrc, ldst, k0, n0;
    u16 *dH = nullptr, *dL = nullptr; float* fdst = nullptr;
    int encw_c = -1;
    if (wb < 1920) {
        int c = wb / 192, rem = wb % 192;
        int kt = rem >> 2, nt = rem & 3;
        k0 = kt * 64; n0 = nt * 64;
        src = encW + (size_t)c * DIN * DD;  lsrc = DD;
        encw_c = c; ldst = 0;
    } else if (wb < 2112) {
        int rem = wb - 1920;
        int kt = rem / 48, nt = rem % 48;
        k0 = kt * 64; n0 = nt * 64;
        src = dW; lsrc = DIN;
        dH = dWtH; dL = dWtL; ldst = DD;
    } else {
        int rem = wb - 2112;          // cb: src rows = codes (512), cols = k (256)
        int kt = rem >> 2, nt = rem & 3;
        k0 = kt * 64; n0 = nt * 64;
        src = cb; lsrc = DD;
        fdst = cbt; ldst = KCB;
    }
    __shared__ float tile[64][65];
    const int trow = t >> 4, tc4 = t & 15;
#pragma unroll
    for (int j = 0; j < 4; ++j) {
        int kk = trow * 4 + j;
        float4 v = *(const float4*)&src[(size_t)(k0 + kk) * lsrc + n0 + tc4 * 4];
        tile[kk][tc4 * 4 + 0] = v.x; tile[kk][tc4 * 4 + 1] = v.y;
        tile[kk][tc4 * 4 + 2] = v.z; tile[kk][tc4 * 4 + 3] = v.w;
    }
    __syncthreads();
    const int n = n0 + (t >> 2), q = t & 3;
    if (fdst) {
#pragma unroll
        for (int j = 0; j < 4; ++j) {
            float4 o = {tile[q * 16 + 4 * j + 0][n - n0], tile[q * 16 + 4 * j + 1][n - n0],
                        tile[q * 16 + 4 * j + 2][n - n0], tile[q * 16 + 4 * j + 3][n - n0]};
            *(float4*)&fdst[(size_t)n * ldst + k0 + q * 16 + 4 * j] = o;
        }
        return;
    }
    s16x8 vh0, vh1, vl0, vl1;
#pragma unroll
    for (int i = 0; i < 8; ++i) {
        u16 h, l;
        f2bf2(tile[q * 16 + i][n - n0], h, l);
        vh0[i] = (short)h; vl0[i] = (short)l;
    }
#pragma unroll
    for (int i = 0; i < 8; ++i) {
        u16 h, l;
        f2bf2(tile[q * 16 + 8 + i][n - n0], h, l);
        vh1[i] = (short)h; vl1[i] = (short)l;
    }
    if (encw_c >= 0) {
        // packed store: [c][nh][ks][it][cg][fg][fr][8]
        const int nh = n >> 7, cg = (n & 127) >> 4, fr2 = n & 15;
        const size_t nbase = (size_t)encw_c * PW_C + (size_t)nh * PW_NH
                           + (size_t)cg * 512 + (size_t)fr2 * 8;
        int ko = (k0 >> 3) + 2 * q;
        {
            int ks2 = ko >> 6, r2 = ko & 63, it2 = r2 >> 2, fg2 = r2 & 3;
            size_t o = nbase + (size_t)ks2 * PW_KS + (size_t)it2 * PW_IT + (size_t)fg2 * 128;
            *(s16x8*)&WtH[o] = vh0; *(s16x8*)&WtL[o] = vl0;
        }
        {
            int ko1 = ko + 1;
            int ks2 = ko1 >> 6, r2 = ko1 & 63, it2 = r2 >> 2, fg2 = r2 & 3;
            size_t o = nbase + (size_t)ks2 * PW_KS + (size_t)it2 * PW_IT + (size_t)fg2 * 128;
            *(s16x8*)&WtH[o] = vh1; *(s16x8*)&WtL[o] = vl1;
        }
        return;
    }
    u16* oH = dH + (size_t)n * ldst + k0 + q * 16;
    u16* oL = dL + (size_t)n * ldst + k0 + q * 16;
    *(s16x8*)oH = vh0; *(s16x8*)(oH + 8) = vh1;
    *(s16x8*)oL = vl0; *(s16x8*)(oL + 8) = vl1;
}

// ---------------- fused encoder GEMM (v4, verified) + decoder GEMM ----------------
// dec split 96->192 blocks (32-row tiles): spreads dec interference over
// ~188 CUs at half per-CU work instead of 92 CUs at full -> makespan delay
// on the critical (enc+dec) CUs roughly halves. dcb bits unchanged (same
// 3-MFMA chain and k-order per output element).
#define ENC_STEP(IT, PB, L0, L1, C0, C1)                                        \
    {                                                                           \
        if ((IT) + 1 < NIT) { asm volatile("s_waitcnt vmcnt(6)" ::: "memory"); } \
        else                { asm volatile("s_waitcnt vmcnt(0)" ::: "memory"); } \
        asm volatile("s_waitcnt lgkmcnt(0)" ::: "memory");                      \
        __builtin_amdgcn_s_barrier();                                           \
        __builtin_amdgcn_sched_barrier(0);                                      \
        s16x8 aH[4], aL[4], bH[4], bL[4];                                       \
        _Pragma("unroll")                                                       \
        for (int mt = 0; mt < 4; ++mt) {                                        \
            aH[mt] = *(const s16x8*)&AsH[(wr * 4 + mt) * 512 + arb];            \
            aL[mt] = *(const s16x8*)&AsL[(wr * 4 + mt) * 512 + arb];            \
        }                                                                       \
        _Pragma("unroll")                                                       \
        for (int ct = 0; ct < 4; ++ct) {                                        \
            bH[ct] = *(const s16x8*)&BsH[PB][ct * 512 + brb];                   \
            bL[ct] = *(const s16x8*)&BsL[PB][ct * 512 + brb];                   \
        }                                                                       \
        asm volatile("s_waitcnt lgkmcnt(0)" ::: "memory");                      \
        __builtin_amdgcn_sched_barrier(0);                                      \
        __builtin_amdgcn_s_barrier();                                           \
        __builtin_amdgcn_sched_barrier(0);                                      \
        if ((IT) + 2 < NIT) {                                                   \
            L0 = *(const float4*)(xp + ((IT) + 2) * 32);                        \
            L1 = *(const float4*)(xp + ((IT) + 2) * 32 + 4);                    \
            __builtin_amdgcn_sched_barrier(0);                                  \
            const u16* g_ = gchunk + (size_t)((IT) + 2) * PW_IT;                \
            u16* l_ = lchunk + (PB) * 8192;                                     \
            _Pragma("unroll")                                                   \
            for (int i = 0; i < 4; ++i) gl16(g_ + i * 512, l_ + i * 512);       \
            __builtin_amdgcn_sched_barrier(0);                                  \
        }                                                                       \
        __builtin_amdgcn_s_setprio(1);                                          \
        _Pragma("unroll")                                                       \
        for (int ct = 0; ct < 4; ++ct) {                                        \
            _Pragma("unroll")                                                   \
            for (int mt = 0; mt < 4; ++mt) {                                    \
                acc[mt][ct] = __builtin_amdgcn_mfma_f32_16x16x32_bf16(aH[mt], bH[ct], acc[mt][ct], 0, 0, 0); \
                acc[mt][ct] = __builtin_amdgcn_mfma_f32_16x16x32_bf16(aL[mt], bH[ct], acc[mt][ct], 0, 0, 0); \
                acc[mt][ct] = __builtin_amdgcn_mfma_f32_16x16x32_bf16(aH[mt], bL[ct], acc[mt][ct], 0, 0, 0); \
            }                                                                   \
        }                                                                       \
        __builtin_amdgcn_s_setprio(0);                                          \
        if ((IT) + 1 < NIT) {                                                   \
            if ((IT) + 2 < NIT) { asm volatile("s_waitcnt vmcnt(10)" ::: "memory"); } \
            else                { asm volatile("s_waitcnt vmcnt(4)"  ::: "memory"); } \
            cvt_store(C0, C1);                                                  \
        }                                                                       \
    }

__global__ __launch_bounds__(512, 2) void k_encdec(
    const float* __restrict__ x, const u16* __restrict__ WpH, const u16* __restrict__ WpL,
    const int* __restrict__ order, const int* __restrict__ meta, float* __restrict__ zpart,
    const float* __restrict__ cb, const u16* __restrict__ dWtH, const u16* __restrict__ dWtL,
    const float* __restrict__ db, float* __restrict__ dcb)
{
    __shared__ __align__(16) u16 smem[40960];   // 81920 B union (enc uses all; dec 46KB)
    const int bid = blockIdx.x;

    if (bid < NENC) {
        // ================= encoder branch (verified v4 body) =================
        const int ks  = bid % KSPLIT;
        const int tid = bid / KSPLIT;
        if (tid >= meta[63]) return;
        const int c    = meta[64 + 2 * tid];
        const int row0 = meta[65 + 2 * tid];
        const int cnt  = meta[c];
        const int off  = meta[32 + c];
        const int kbase = ks * KC;

        u16* AsH = smem;                                    // [4096]
        u16* AsL = smem + 4096;                             // [4096]
        u16 (*BsH)[8192] = (u16(*)[8192])(smem + 8192);     // [2][8192]
        u16 (*BsL)[8192] = (u16(*)[8192])(smem + 24576);    // [2][8192]

        const int t = threadIdx.x;
        const int lane = t & 63;
        const int w    = t >> 6;              // wave id 0..7
        const int wr = w >> 2, wc = w & 3;    // wave tile: rows wr*64, cols wc*64
        const int fr = lane & 15, fg = lane >> 4;

        // ---- A staging: thread t -> (row ar, k-octet aq); LDS write linear t*16B
        const int ar = ((t >> 6) << 4) | (t & 15);   // 0..127
        const int aq = (t >> 4) & 3;
        int lr = row0 + ar; if (lr > cnt - 1) lr = cnt - 1;
        const float* xp = x + (size_t)order[off + lr] * DIN + kbase + aq * 8;
        const int aoffs = t * 8;

        // ---- B DMA: wave w copies one 4KB chunk/iter:
        //   waves 0-3 -> H plane, 4-7 -> L; nh = w&1, half = (w>>1)&1
        const u16* gchunk = ((w >> 2) ? WpL : WpH)
                          + (size_t)c * PW_C + (size_t)(w & 1) * PW_NH
                          + (size_t)ks * PW_KS + ((w >> 1) & 1) * 2048 + lane * 8;
        u16* lchunk = ((w >> 2) ? &BsL[0][0] : &BsH[0][0])
                    + (w & 1) * 4096 + ((w >> 1) & 1) * 2048 + lane * 8;

        f32x4 acc[4][4];
#pragma unroll
        for (int i = 0; i < 4; ++i)
#pragma unroll
            for (int j = 0; j < 4; ++j) acc[i][j] = (f32x4){0.f, 0.f, 0.f, 0.f};

        auto cvt_store = [&](float4 a0, float4 a1) {
            float av[8] = {a0.x, a0.y, a0.z, a0.w, a1.x, a1.y, a1.z, a1.w};
            s16x8 vh, vl;
#pragma unroll
            for (int i = 0; i < 8; ++i) {
                u16 h, l; f2bf2(av[i], h, l);
                vh[i] = (short)h; vl[i] = (short)l;
            }
            *(s16x8*)&AsH[aoffs] = vh;
            *(s16x8*)&AsL[aoffs] = vl;
        };

        const int arb = fg * 128 + fr * 8;                            // A frag base
        const int brb = (wc >> 1) * 4096 + (wc & 1) * 2048 + arb;     // B frag base (within buf)

        float4 sa0, sa1, sb0, sb1;

        // ---- prologue: pa(0); B(0)->buf0; cvt A(0); pa(1); B(1)->buf1
        sa0 = *(const float4*)xp;
        sa1 = *(const float4*)(xp + 4);
        __builtin_amdgcn_sched_barrier(0);
#pragma unroll
        for (int i = 0; i < 4; ++i) gl16(gchunk + i * 512, lchunk + i * 512);
        __builtin_amdgcn_sched_barrier(0);
        asm volatile("s_waitcnt vmcnt(4)" ::: "memory");   // pa(0) done, B(0) in flight
        cvt_store(sa0, sa1);
        __builtin_amdgcn_sched_barrier(0);
        sb0 = *(const float4*)(xp + 32);
        sb1 = *(const float4*)(xp + 36);
        __builtin_amdgcn_sched_barrier(0);
#pragma unroll
        for (int i = 0; i < 4; ++i) gl16(gchunk + PW_IT + i * 512, lchunk + 8192 + i * 512);
        __builtin_amdgcn_sched_barrier(0);

        for (int itp = 0; itp < NIT; itp += 2) {
            ENC_STEP(itp,     0, sa0, sa1, sb0, sb1);
            ENC_STEP(itp + 1, 1, sb0, sb1, sa0, sa1);
        }

        float* zp = zpart + (size_t)ks * NB * DD;
#pragma unroll
        for (int mt = 0; mt < 4; ++mt) {
#pragma unroll
            for (int r = 0; r < 4; ++r) {
                int lrow = row0 + wr * 64 + mt * 16 + fg * 4 + r;
                if (lrow < cnt) {
                    int gb = order[off + lrow];
                    float* dst = zp + (size_t)gb * DD + wc * 64 + fr;
#pragma unroll
                    for (int ct = 0; ct < 4; ++ct)
                        dst[ct * 16] = acc[mt][ct][r];
                }
            }
        }
        return;
    }

    // ================= decoder branch (32-row tiles, 192 blocks) =================
    {
        const int bid2 = bid - NENC;          // 0..191
        const int col0 = (bid2 % 12) * 256;
        const int m0   = (bid2 / 12) * 32;

        u16* AsH = smem;                      // [32*40] = 1280
        u16* AsL = smem + 1280;               // 1280
        u16* BsH = smem + 2560;               // [256*40] = 10240
        u16* BsL = smem + 12800;              // 10240 (ends 23040 u16 = 46080 B)

        const int t = threadIdx.x;            // 0..511
        const int lane = t & 63;
        const int w8  = t >> 6;               // 0..7
        const int wr = w8 >> 2, wc = w8 & 3;  // wave tile: rows wr*16, cols wc*64

        const int ar = t >> 4, aq = t & 15;   // A: row ar(0..31), 2-float granule aq
        const float* ap = cb + (size_t)(m0 + ar) * DD + aq * 2;
        const int bc = t >> 1, bh = t & 1;    // B: col bc(0..255), k-half bh
        const u16* wH0 = dWtH + (size_t)(col0 + bc) * DD + bh * 16;
        const u16* wL0 = dWtL + (size_t)(col0 + bc) * DD + bh * 16;

        f32x4 acc4[4];
#pragma unroll
        for (int j = 0; j < 4; ++j) acc4[j] = (f32x4){0.f, 0.f, 0.f, 0.f};

        const int fr = lane & 15, fg = lane >> 4;
        const int aoff = fg * 8;
        const int awr = ar * 40 + aq * 2;
        const int bw0 = bc * 40 + bh * 16;

        float2 pa0 = *(const float2*)(ap);
        s16x8 ph0 = *(const s16x8*)(wH0);
        s16x8 ph1 = *(const s16x8*)(wH0 + 8);
        s16x8 pl0 = *(const s16x8*)(wL0);
        s16x8 pl1 = *(const s16x8*)(wL0 + 8);

        for (int it = 0; it < DD / 32; ++it) {
            {
                u16 h0, l0, h1, l1;
                f2bf2(pa0.x, h0, l0);
                f2bf2(pa0.y, h1, l1);
                s16x2 vh = { (short)h0, (short)h1 };
                s16x2 vl = { (short)l0, (short)l1 };
                *(s16x2*)&AsH[awr] = vh;
                *(s16x2*)&AsL[awr] = vl;
                *(s16x8*)&BsH[bw0]     = ph0;
                *(s16x8*)&BsH[bw0 + 8] = ph1;
                *(s16x8*)&BsL[bw0]     = pl0;
                *(s16x8*)&BsL[bw0 + 8] = pl1;
            }
            __syncthreads();
            if (it + 1 < DD / 32) {
                const int k0 = (it + 1) * 32;
                pa0 = *(const float2*)(ap + k0);
                ph0 = *(const s16x8*)(wH0 + k0);
                ph1 = *(const s16x8*)(wH0 + k0 + 8);
                pl0 = *(const s16x8*)(wL0 + k0);
                pl1 = *(const s16x8*)(wL0 + k0 + 8);
            }
            s16x8 aH0 = *(const s16x8*)&AsH[(wr * 16 + fr) * 40 + aoff];
            s16x8 aL0 = *(const s16x8*)&AsL[(wr * 16 + fr) * 40 + aoff];
#pragma unroll
            for (int nt = 0; nt < 4; ++nt) {
                const int bcol = wc * 64 + nt * 16 + fr;
                s16x8 bH = *(const s16x8*)&BsH[bcol * 40 + aoff];
                s16x8 bL = *(const s16x8*)&BsL[bcol * 40 + aoff];
                acc4[nt] = __builtin_amdgcn_mfma_f32_16x16x32_bf16(aH0, bH, acc4[nt], 0, 0, 0);
                acc4[nt] = __builtin_amdgcn_mfma_f32_16x16x32_bf16(aL0, bH, acc4[nt], 0, 0, 0);
                acc4[nt] = __builtin_amdgcn_mfma_f32_16x16x32_bf16(aH0, bL, acc4[nt], 0, 0, 0);
            }
            __syncthreads();
        }

#pragma unroll
        for (int r = 0; r < 4; ++r) {
            int grow = m0 + wr * 16 + fg * 4 + r;
            float* dst = dcb + (size_t)grow * DIN + col0 + wc * 64 + fr;
#pragma unroll
            for (int nt = 0; nt < 4; ++nt)
                dst[nt * 16] = acc4[nt][r] + db[col0 + wc * 64 + nt * 16 + fr];
        }
    }
}

// ---------------- VQ scores (k_zred fused in: z recomputed from zpart) ----------------
// z slice computed per block with EXACT zred add order (encB then ks 0..5,
// same 4-col granules) -> bitwise identical z -> identical argmin. VERIFIED
// R10/R11 (passed, absmax 0.015625).
__global__ __launch_bounds__(256) void k_vq(
    const float* __restrict__ zpart, const float* __restrict__ encB,
    const int* __restrict__ label, const float* __restrict__ cbt,
    const float* __restrict__ cbn, float* __restrict__ vmin,
    int* __restrict__ vidx, float* __restrict__ zn)
{
    const int sg = blockIdx.x >> 2;
    const int q  = blockIdx.x & 3;
    const int b0 = sg * 32;
    const int code0 = q * 128;

    __shared__ float As[32][36];
    __shared__ float Bs[32][132];

    const int t = threadIdx.x;
    const int tx = t & 31, ty = t >> 5;

    const int ar = t >> 3, akq = t & 7;
    const float* zpb = zpart + (size_t)(b0 + ar) * DD + akq * 4;
    const float* ebp = encB + (size_t)label[b0 + ar] * DD + akq * 4;
    const int bkk = t >> 3, bcq = t & 7;
    const float* cp = cbt + (size_t)bkk * KCB + code0 + bcq * 16;

    auto loadz = [&](int it) -> float4 {
        float4 s = *(const float4*)(ebp + it * 32);
#pragma unroll
        for (int ks = 0; ks < KSPLIT; ++ks) {
            float4 v = *(const float4*)(zpb + (size_t)ks * NB * DD + it * 32);
            s.x += v.x; s.y += v.y; s.z += v.z; s.w += v.w;
        }
        return s;
    };

    float acc[4][4];
#pragma unroll
    for (int i = 0; i < 4; ++i)
#pragma unroll
        for (int j = 0; j < 4; ++j) acc[i][j] = 0.f;

    float sqa = 0.f;
    float4 pa  = loadz(0);
    float4 pb0 = *(const float4*)(cp);
    float4 pb1 = *(const float4*)(cp + 4);
    float4 pb2 = *(const float4*)(cp + 8);
    float4 pb3 = *(const float4*)(cp + 12);

    for (int it = 0; it < DD / 32; ++it) {
        As[akq * 4 + 0][ar] = pa.x;
        As[akq * 4 + 1][ar] = pa.y;
        As[akq * 4 + 2][ar] = pa.z;
        As[akq * 4 + 3][ar] = pa.w;
        sqa = fmaf(pa.x, pa.x, fmaf(pa.y, pa.y, fmaf(pa.z, pa.z, fmaf(pa.w, pa.w, sqa))));
        *(float4*)&Bs[bkk][bcq * 16]      = pb0;
        *(float4*)&Bs[bkk][bcq * 16 + 4]  = pb1;
        *(float4*)&Bs[bkk][bcq * 16 + 8]  = pb2;
        *(float4*)&Bs[bkk][bcq * 16 + 12] = pb3;
        __syncthreads();
        if (it + 1 < DD / 32) {
            const float* cpn = cp + (size_t)(it + 1) * 32 * KCB;
            pa  = loadz(it + 1);
            pb0 = *(const float4*)(cpn);
            pb1 = *(const float4*)(cpn + 4);
            pb2 = *(const float4*)(cpn + 8);
            pb3 = *(const float4*)(cpn + 12);
        }
#pragma unroll
        for (int kk = 0; kk < 32; ++kk) {
            float4 a4 = *(const float4*)&As[kk][ty * 4];
            float4 b4 = *(const float4*)&Bs[kk][tx * 4];
            float am[4] = {a4.x, a4.y, a4.z, a4.w};
            float bn[4] = {b4.x, b4.y, b4.z, b4.w};
#pragma unroll
            for (int i = 0; i < 4; ++i)
#pragma unroll
                for (int j = 0; j < 4; ++j)
                    acc[i][j] = fmaf(am[i], bn[j], acc[i][j]);
        }
        __syncthreads();
    }

    // zn: reduce the per-thread 32-col partials across the 8 lanes of each row
#pragma unroll
    for (int o = 4; o > 0; o >>= 1) sqa += __shfl_down(sqa, o, 8);
    if ((t & 7) == 0) zn[b0 + ar] = sqa;

    float4 cn4 = *(const float4*)&cbn[code0 + tx * 4];
    float cnv[4] = {cn4.x, cn4.y, cn4.z, cn4.w};
#pragma unroll
    for (int i = 0; i < 4; ++i) {
        float m = cnv[0] - 2.f * acc[i][0];
        int bi = code0 + tx * 4;
#pragma unroll
        for (int j = 1; j < 4; ++j) {
            float sc = cnv[j] - 2.f * acc[i][j];
            if (sc < m) { m = sc; bi = code0 + tx * 4 + j; }
        }
#pragma unroll
        for (int mask = 1; mask <= 16; mask <<= 1) {
            float om = __shfl_xor(m, mask, 64);
            int   oi = __shfl_xor(bi, mask, 64);
            bool lowerSelf = (tx & mask) == 0;
            float lm = lowerSelf ? m : om;
            int   li = lowerSelf ? bi : oi;
            float hm = lowerSelf ? om : m;
            int   hi2 = lowerSelf ? oi : bi;
            if (hm < lm) { m = hm; bi = hi2; } else { m = lm; bi = li; }
        }
        if (tx == 0) {
            vmin[(size_t)(b0 + ty * 4 + i) * 4 + q] = m;
            vidx[(size_t)(b0 + ty * 4 + i) * 4 + q] = bi;
        }
    }
}

// ---------------- gather decoded rows + SSE partials (R9-verified, NO fence) ----------------
__global__ __launch_bounds__(256) void k_gather(
    const float* __restrict__ dcb, const float* __restrict__ vmin, const int* __restrict__ vidx,
    const float* __restrict__ zn, const float* __restrict__ img,
    float* __restrict__ out1, float* __restrict__ ssep, float* __restrict__ lo)
{
    const int b = blockIdx.x;
    // inline quarter merge (identical order/tie-break to old k_vqm)
    float m = vmin[(size_t)b * 4]; int k = vidx[(size_t)b * 4];
#pragma unroll
    for (int q = 1; q < 4; ++q) {
        float v = vmin[(size_t)b * 4 + q];
        if (v < m) { m = v; k = vidx[(size_t)b * 4 + q]; }
    }
    if (threadIdx.x == 0) lo[b] = (zn[b] + m) * (1.25f / 256.f);

    const float* src = dcb + (size_t)k * DIN;
    const float* im  = img + (size_t)b * DIN;
    float* o = out1 + (size_t)b * DIN;   // out1 = d_out + 1
    const float4* s4 = (const float4*)src;
    const float4* i4 = (const float4*)im;

    float accv = 0.f;
#pragma unroll
    for (int j = 0; j < 3; ++j) {
        int i = threadIdx.x + j * 256;
        float4 v = s4[i], w = i4[i];
        float dx = v.x - w.x, dy = v.y - w.y, dz = v.z - w.z, dw = v.w - w.w;
        accv = fmaf(dx, dx, fmaf(dy, dy, fmaf(dz, dz, fmaf(dw, dw, accv))));
    }
#pragma unroll
    for (int j = 0; j < 3; ++j) {
        int i = threadIdx.x + j * 256;
        if (i < DIN / 4 - 1) {
            float4 a = s4[i], b2 = s4[i + 1];
            float4 ov = {a.w, b2.x, b2.y, b2.z};
            *(float4*)(o + 3 + 4 * i) = ov;
        }
    }
    if (threadIdx.x == 0) {
        o[0] = src[0]; o[1] = src[1]; o[2] = src[2];
        o[DIN - 1] = src[DIN - 1];
    }

    __shared__ float red[256];
    red[threadIdx.x] = accv;
    __syncthreads();
#pragma unroll
    for (int st = 128; st > 0; st >>= 1) {
        if (threadIdx.x < st) red[threadIdx.x] += red[threadIdx.x + st];
        __syncthreads();
    }
    if (threadIdx.x == 0) ssep[b] = red[0];
}

// ---------------- final deterministic reduction (wave-shuffle, R9-verified) ----------------
__global__ __launch_bounds__(256) void k_final(
    const float* __restrict__ ssep, const float* __restrict__ lo, const int* __restrict__ label,
    const int* __restrict__ meta, float* __restrict__ out)
{
    const int t = threadIdx.x;
    __shared__ float part[4][12];   // 4 waves x (sse + 10 class sums)

    float se = 0.f;
    float la[NC];
#pragma unroll
    for (int c = 0; c < NC; ++c) la[c] = 0.f;
    for (int b = t; b < NB; b += 256) {
        se += ssep[b];
        int c2 = label[b]; float v = lo[b];
#pragma unroll
        for (int cc = 0; cc < NC; ++cc) la[cc] += (cc == c2) ? v : 0.f;
    }

#pragma unroll
    for (int o = 32; o > 0; o >>= 1) se += __shfl_down(se, o, 64);
#pragma unroll
    for (int cc = 0; cc < NC; ++cc) {
#pragma unroll
        for (int o = 32; o > 0; o >>= 1) la[cc] += __shfl_down(la[cc], o, 64);
    }
    if ((t & 63) == 0) {
        const int wv = t >> 6;
        part[wv][0] = se;
#pragma unroll
        for (int cc = 0; cc < NC; ++cc) part[wv][1 + cc] = la[cc];
    }
    __syncthreads();

    if (t == 0) {
        float sse = part[0][0] + part[1][0] + part[2][0] + part[3][0];
        float quant = 0.f, nact = 0.f;
        for (int cc = 0; cc < NC; ++cc) {
            float cs = part[0][1 + cc] + part[1][1 + cc] + part[2][1 + cc] + part[3][1 + cc];
            int cnt = meta[cc];
            if (cnt > 0) { quant += cs / (float)cnt; nact += 1.f; }
        }
        if (nact < 1.f) nact = 1.f;
        quant /= nact;
        out[0] = sse / (float)(NB * DIN) + quant;
    }
}

extern "C" void kernel_launch(void* const* d_in, const int* in_sizes, int n_in,
                              void* d_out, int out_size, void* d_ws, size_t ws_size,
                              hipStream_t stream)
{
    const float* img   = (const float*)d_in[0];
    const int*   label = (const int*)d_in[1];
    const float* encW  = (const float*)d_in[2];
    const float* encB  = (const float*)d_in[3];
    const float* cb    = (const float*)d_in[4];
    const float* dW    = (const float*)d_in[5];
    const float* db    = (const float*)d_in[6];
    float* out = (float*)d_out;

    char* w = (char*)d_ws;
    float* zpart = (float*)(w);                       // 25,165,824 (6*4096*256*4)
    float* dcb   = (float*)(w + 25165824);            // 6,291,456 (512*3072*4)
    u16*   WtH   = (u16*)  (w + 37748736);            // 15,728,640 (packed)
    u16*   WtL   = (u16*)  (w + 53477376);            // 15,728,640 (packed)
    u16*   dWtH  = (u16*)  (w + 69206016);            // 1,572,864
    u16*   dWtL  = (u16*)  (w + 70778880);            // 1,572,864
    float* vmin  = (float*)(w + 72351744);            // 65,536
    int*   vidx  = (int*)  (w + 72417280);            // 65,536
    float* zn    = (float*)(w + 72482816);            // 16,384
    float* lo    = (float*)(w + 72499200);            // 16,384
    float* ssep  = (float*)(w + 72515584);            // 16,384
    int*   order = (int*)  (w + 72548352);            // 16,384
    int*   meta  = (int*)  (w + 72564736);            // 4,096 (counts/offsets/tilemap)
    float* cbn   = (float*)(w + 72568832);            // 2,048
    float* cbt   = (float*)(w + 72570880);            // 524,288 (256 x 512 f32)

    hipLaunchKernelGGL(k_wtp,    dim3(2147),        dim3(256), 0, stream,
                       label, cb, encW, dW, meta, order, cbn, WtH, WtL, dWtH, dWtL, cbt);
    hipLaunchKernelGGL(k_encdec, dim3(NENC + NDEC), dim3(512), 0, stream,
                       img, WtH, WtL, order, meta, zpart, cb, dWtH, dWtL, db, dcb);
    hipLaunchKernelGGL(k_vq,     dim3(512),         dim3(256), 0, stream,
                       zpart, encB, label, cbt, cbn, vmin, vidx, zn);
    hipLaunchKernelGGL(k_gather, dim3(4096),        dim3(256), 0, stream,
                       dcb, vmin, vidx, zn, img, out + 1, ssep, lo);
    hipLaunchKernelGGL(k_final,  dim3(1),           dim3(256), 0, stream, ssep, lo, label, meta, out);
}